// Round 1
// baseline (355.106 us; speedup 1.0000x reference)
//
#include <hip/hip_runtime.h>
#include <hip/hip_bf16.h>

#define BDIM 384
#define DDIM 1024
#define LDIM 16
#define WD 300
#define NROWS (BDIM * LDIM)  // 6144

// ---------------- tok resolve: tok_eff per (b,l) row, -1 if invalid ----------------
__global__ void tok_kernel(const int* __restrict__ ntid, const int* __restrict__ nlen,
                           const int* __restrict__ ant, const int* __restrict__ t2i,
                           int* __restrict__ rowtok) {
    int i = blockIdx.x * 256 + threadIdx.x;
    if (i >= NROWS) return;
    int b = i >> 4, l = i & 15;
    int tok = ntid[i];
    int w = t2i[tok];
    int eff = (w > 0) ? ant[w] : tok;   // `if weight_idx:` falsy-0 semantics
    rowtok[i] = (l < nlen[b]) ? eff : -1;
}

// ---------------- generic 64x64 tiled fp32 GEMM: C[M][1024] = A@W + bias ----------------
// GATHER: A rows come from embed[rowtok[gr]] (K=300), invalid rows -> 0
template <int K_DIM, bool GATHER, bool RELU>
__global__ __launch_bounds__(256) void gemm64(const float* __restrict__ A,
                                              const int* __restrict__ rowtok,
                                              const float* __restrict__ W,
                                              const float* __restrict__ bias,
                                              float* __restrict__ C) {
    constexpr int BK = 16;
    constexpr int KT = (K_DIM + BK - 1) / BK;
    __shared__ float As[BK][68];  // transposed A tile, +4 pad (16B-aligned float4 rows)
    __shared__ float Bs[BK][64];
    __shared__ int stok[64];

    const int tid = threadIdx.x;
    const int bm = blockIdx.x * 64;
    const int bn = blockIdx.y * 64;

    if (GATHER && tid < 64) stok[tid] = rowtok[bm + tid];
    __syncthreads();

    const int arow = tid >> 4;  // A-load: rows arow + e*16, k = ak
    const int ak = tid & 15;
    const int bcol = tid & 63;  // B-load: col, k = bk0 + e*4
    const int bk0 = tid >> 6;
    const int ty = tid >> 4, tx = tid & 15;

    int tokreg[4];
    if (GATHER) {
#pragma unroll
        for (int e = 0; e < 4; ++e) tokreg[e] = stok[arow + e * 16];
    }

    float acc[4][4] = {};

    for (int kt = 0; kt < KT; ++kt) {
        const int k0 = kt * BK;
#pragma unroll
        for (int e = 0; e < 4; ++e) {
            int row = arow + e * 16;
            float vA = 0.f;
            if (GATHER) {
                int tok = tokreg[e];
                if (tok >= 0 && (K_DIM % BK == 0 || k0 + ak < K_DIM))
                    vA = A[tok * WD + k0 + ak];
            } else {
                vA = A[(size_t)(bm + row) * K_DIM + k0 + ak];
            }
            As[ak][row] = vA;

            int kb = bk0 + e * 4;
            float vB = 0.f;
            if (K_DIM % BK == 0 || k0 + kb < K_DIM)
                vB = W[(size_t)(k0 + kb) * DDIM + bn + bcol];
            Bs[kb][bcol] = vB;
        }
        __syncthreads();
#pragma unroll
        for (int kk = 0; kk < BK; ++kk) {
            const float4 a4 = *(const float4*)&As[kk][ty * 4];
            const float4 b4 = *(const float4*)&Bs[kk][tx * 4];
            const float av[4] = {a4.x, a4.y, a4.z, a4.w};
            const float bv[4] = {b4.x, b4.y, b4.z, b4.w};
#pragma unroll
            for (int i = 0; i < 4; ++i)
#pragma unroll
                for (int j = 0; j < 4; ++j) acc[i][j] += av[i] * bv[j];
        }
        __syncthreads();
    }

#pragma unroll
    for (int i = 0; i < 4; ++i) {
        int row = bm + ty * 4 + i;
        bool zero = false;
        if (GATHER) zero = (stok[ty * 4 + i] < 0);
        float4 o;
        float* po = &o.x;
#pragma unroll
        for (int j = 0; j < 4; ++j) {
            float val = acc[i][j] + bias[bn + tx * 4 + j];
            if (RELU) val = fmaxf(val, 0.f);
            po[j] = zero ? 0.f : val;
        }
        *(float4*)&C[(size_t)row * DDIM + bn + tx * 4] = o;
    }
}

// ---------------- block reductions (256 threads = 4 waves) ----------------
__device__ inline float bred_sum(float x, float* sbuf) {
#pragma unroll
    for (int off = 32; off; off >>= 1) x += __shfl_down(x, off);
    __syncthreads();
    if ((threadIdx.x & 63) == 0) sbuf[threadIdx.x >> 6] = x;
    __syncthreads();
    return sbuf[0] + sbuf[1] + sbuf[2] + sbuf[3];
}
__device__ inline float bred_max(float x, float* sbuf) {
#pragma unroll
    for (int off = 32; off; off >>= 1) x = fmaxf(x, __shfl_down(x, off));
    __syncthreads();
    if ((threadIdx.x & 63) == 0) sbuf[threadIdx.x >> 6] = x;
    __syncthreads();
    return fmaxf(fmaxf(sbuf[0], sbuf[1]), fmaxf(sbuf[2], sbuf[3]));
}

// ---------------- rowops: softmax(S2), l2norm(Tr) -> u, v; inv norms of r,t ----------------
__global__ __launch_bounds__(256) void rowops(const float* __restrict__ S2,
                                              const float* __restrict__ Tr,
                                              const float* __restrict__ rr,
                                              const float* __restrict__ tt,
                                              float* __restrict__ u, float* __restrict__ v,
                                              float* __restrict__ inv_r,
                                              float* __restrict__ inv_t) {
    __shared__ float sbuf[4];
    const int b = blockIdx.x, tid = threadIdx.x;
    const size_t base = (size_t)b * DDIM + tid * 4;

    const float4 s4 = *(const float4*)&S2[base];
    float mx = fmaxf(fmaxf(s4.x, s4.y), fmaxf(s4.z, s4.w));
    mx = bred_max(mx, sbuf);
    float e0 = expf(s4.x - mx), e1 = expf(s4.y - mx), e2 = expf(s4.z - mx), e3 = expf(s4.w - mx);
    float sum = bred_sum(e0 + e1 + e2 + e3, sbuf);
    float invsum = 1.f / sum;

    const float4 tr4 = *(const float4*)&Tr[base];
    float ss = tr4.x * tr4.x + tr4.y * tr4.y + tr4.z * tr4.z + tr4.w * tr4.w;
    ss = bred_sum(ss, sbuf);
    float invn = 1.f / sqrtf(ss);

    float a0 = e0 * invsum, a1 = e1 * invsum, a2 = e2 * invsum, a3 = e3 * invsum;
    float4 u4, v4;
    u4.x = tr4.x * invn * a0; u4.y = tr4.y * invn * a1;
    u4.z = tr4.z * invn * a2; u4.w = tr4.w * invn * a3;
    v4.x = a0 * a0; v4.y = a1 * a1; v4.z = a2 * a2; v4.w = a3 * a3;
    *(float4*)&u[base] = u4;
    *(float4*)&v[base] = v4;

    const float4 r4 = *(const float4*)&rr[base];
    float sr = bred_sum(r4.x * r4.x + r4.y * r4.y + r4.z * r4.z + r4.w * r4.w, sbuf);
    const float4 t4 = *(const float4*)&tt[base];
    float st = bred_sum(t4.x * t4.x + t4.y * t4.y + t4.z * t4.z + t4.w * t4.w, sbuf);
    if (tid == 0) {
        inv_r[b] = 1.f / sqrtf(sr);
        inv_t[b] = 1.f / sqrtf(st);
    }
}

// ---------------- score: fused 3-dot 384x384, K=1024 ----------------
__global__ __launch_bounds__(256) void score_kernel(
    const float* __restrict__ u, const float* __restrict__ v, const float* __restrict__ rr,
    const float* __restrict__ tt, const float* __restrict__ inv_r,
    const float* __restrict__ inv_t, float* __restrict__ out) {
    __shared__ float Us[16][68], Vs[16][68], Rs[16][68], Ts[16][68];
    const int tid = threadIdx.x;
    const int bm = blockIdx.x * 64, bn = blockIdx.y * 64;
    const int lrow = tid >> 4, lk = tid & 15;
    const int ty = tid >> 4, tx = tid & 15;

    float acc1[4][4] = {}, acc2[4][4] = {}, acc3[4][4] = {};

    for (int kt = 0; kt < DDIM / 16; ++kt) {
        const int k0 = kt * 16;
#pragma unroll
        for (int e = 0; e < 4; ++e) {
            int row = lrow + e * 16;
            Us[lk][row] = u[(size_t)(bm + row) * DDIM + k0 + lk];
            Vs[lk][row] = v[(size_t)(bm + row) * DDIM + k0 + lk];
            Rs[lk][row] = rr[(size_t)(bm + row) * DDIM + k0 + lk];
            Ts[lk][row] = tt[(size_t)(bn + row) * DDIM + k0 + lk];
        }
        __syncthreads();
#pragma unroll
        for (int kk = 0; kk < 16; ++kk) {
            const float4 u4 = *(const float4*)&Us[kk][ty * 4];
            const float4 v4 = *(const float4*)&Vs[kk][ty * 4];
            const float4 r4 = *(const float4*)&Rs[kk][ty * 4];
            const float4 t4 = *(const float4*)&Ts[kk][tx * 4];
            const float uu[4] = {u4.x, u4.y, u4.z, u4.w};
            const float vv[4] = {v4.x, v4.y, v4.z, v4.w};
            const float rv[4] = {r4.x, r4.y, r4.z, r4.w};
            const float tv[4] = {t4.x, t4.y, t4.z, t4.w};
            const float t2[4] = {tv[0] * tv[0], tv[1] * tv[1], tv[2] * tv[2], tv[3] * tv[3]};
#pragma unroll
            for (int i = 0; i < 4; ++i)
#pragma unroll
                for (int j = 0; j < 4; ++j) {
                    acc1[i][j] += uu[i] * tv[j];
                    acc2[i][j] += vv[i] * t2[j];
                    acc3[i][j] += rv[i] * tv[j];
                }
        }
        __syncthreads();
    }

#pragma unroll
    for (int i = 0; i < 4; ++i) {
        int row = bm + ty * 4 + i;
        float ir = inv_r[row];
        float4 o;
        float* po = &o.x;
#pragma unroll
        for (int j = 0; j < 4; ++j) {
            int col = bn + tx * 4 + j;
            po[j] = acc1[i][j] / sqrtf(acc2[i][j]) + acc3[i][j] * ir * inv_t[col];
        }
        *(float4*)&out[(size_t)row * BDIM + bn + tx * 4] = o;
    }
}

extern "C" void kernel_launch(void* const* d_in, const int* in_sizes, int n_in, void* d_out,
                              int out_size, void* d_ws, size_t ws_size, hipStream_t stream) {
    const float* r = (const float*)d_in[0];
    const float* m = (const float*)d_in[1];
    const float* t = (const float*)d_in[2];
    const int* ntid = (const int*)d_in[3];
    const int* nlen = (const int*)d_in[4];
    const int* ant = (const int*)d_in[5];
    const float* embed = (const float*)d_in[6];
    const float* noun_W = (const float*)d_in[7];
    const float* noun_b = (const float*)d_in[8];
    const float* em_W1 = (const float*)d_in[9];
    const float* em_b1 = (const float*)d_in[10];
    const float* em_W2 = (const float*)d_in[11];
    const float* em_b2 = (const float*)d_in[12];
    const float* tr_W = (const float*)d_in[13];
    const float* tr_b = (const float*)d_in[14];
    const int* t2i = (const int*)d_in[15];

    float* score = (float*)d_out;
    float* concepts = score + (size_t)BDIM * BDIM;

    const size_t F = (size_t)BDIM * DDIM;
    char* wp = (char*)d_ws;
    int* rowtok = (int*)wp;      wp += NROWS * sizeof(int);
    float* h = (float*)wp;       wp += F * sizeof(float);
    float* S2 = (float*)wp;      wp += F * sizeof(float);
    float* Tr = (float*)wp;      wp += F * sizeof(float);
    float* u = (float*)wp;       wp += F * sizeof(float);
    float* v = (float*)wp;       wp += F * sizeof(float);
    float* inv_r = (float*)wp;   wp += BDIM * sizeof(float);
    float* inv_t = (float*)wp;

    tok_kernel<<<(NROWS + 255) / 256, 256, 0, stream>>>(ntid, nlen, ant, t2i, rowtok);

    dim3 gC(NROWS / 64, DDIM / 64);  // 96 x 16
    gemm64<WD, true, false><<<gC, 256, 0, stream>>>(embed, rowtok, noun_W, noun_b, concepts);

    dim3 gE(BDIM / 64, DDIM / 64);  // 6 x 16
    gemm64<DDIM, false, true><<<gE, 256, 0, stream>>>(m, nullptr, em_W1, em_b1, h);
    gemm64<DDIM, false, false><<<gE, 256, 0, stream>>>(h, nullptr, em_W2, em_b2, S2);
    gemm64<DDIM, false, false><<<gE, 256, 0, stream>>>(m, nullptr, tr_W, tr_b, Tr);

    rowops<<<BDIM, 256, 0, stream>>>(S2, Tr, r, t, u, v, inv_r, inv_t);

    dim3 gS(BDIM / 64, BDIM / 64);  // 6 x 6
    score_kernel<<<gS, 256, 0, stream>>>(u, v, r, t, inv_r, inv_t, score);
}

// Round 2
// 213.294 us; speedup vs baseline: 1.6649x; 1.6649x over previous
//
#include <hip/hip_runtime.h>
#include <hip/hip_bf16.h>

#define BDIM 384
#define DDIM 1024
#define LDIM 16
#define WD 300
#define NROWS (BDIM * LDIM)   // 6144
#define FELEM (BDIM * DDIM)   // 393216
#define SELEM (BDIM * BDIM)   // 147456

// ---------------- tok resolve: tok_eff per (b,l) row, -1 if invalid ----------------
__global__ void tok_kernel(const int* __restrict__ ntid, const int* __restrict__ nlen,
                           const int* __restrict__ ant, const int* __restrict__ t2i,
                           int* __restrict__ rowtok) {
    int i = blockIdx.x * 256 + threadIdx.x;
    if (i >= NROWS) return;
    int b = i >> 4, l = i & 15;
    int tok = ntid[i];
    int w = t2i[tok];
    int eff = (w > 0) ? ant[w] : tok;   // `if weight_idx:` falsy-0 semantics
    rowtok[i] = (l < nlen[b]) ? eff : -1;
}

// ---------------- concepts: 128x128 tile, 8x8 micro, gathered A (K=300) ----------------
__global__ __launch_bounds__(256) void gemm128_gather(const float* __restrict__ embed,
                                                      const int* __restrict__ rowtok,
                                                      const float* __restrict__ W,
                                                      const float* __restrict__ bias,
                                                      float* __restrict__ C) {
    __shared__ float As[16][132];   // transposed A tile (k, row), +4 pad
    __shared__ float Bs[16][128];
    __shared__ int stok[128];

    const int tid = threadIdx.x;
    const int bm = blockIdx.x * 128;
    const int bn = blockIdx.y * 128;

    if (tid < 128) stok[tid] = rowtok[bm + tid];
    __syncthreads();

    const int ak = tid & 15, arow0 = tid >> 4;      // A: rows arow0+e*16, k=ak
    const int bcol = tid & 127, bk0 = tid >> 7;     // B: k = bk0+e*2, col=bcol
    const int ty = tid >> 4, tx = tid & 15;

    int tokreg[8];
#pragma unroll
    for (int e = 0; e < 8; ++e) tokreg[e] = stok[arow0 + e * 16];

    float acc[8][8] = {};
    constexpr int KT = (WD + 15) / 16;  // 19

    for (int kt = 0; kt < KT; ++kt) {
        const int k0 = kt * 16;
#pragma unroll
        for (int e = 0; e < 8; ++e) {
            int row = arow0 + e * 16;
            int tok = tokreg[e];
            float vA = 0.f;
            if (tok >= 0 && k0 + ak < WD) vA = embed[(size_t)tok * WD + k0 + ak];
            As[ak][row] = vA;

            int kb = bk0 + e * 2;
            float vB = (k0 + kb < WD) ? W[(size_t)(k0 + kb) * DDIM + bn + bcol] : 0.f;
            Bs[kb][bcol] = vB;
        }
        __syncthreads();
#pragma unroll
        for (int kk = 0; kk < 16; ++kk) {
            const float4 a0 = *(const float4*)&As[kk][ty * 4];
            const float4 a1 = *(const float4*)&As[kk][64 + ty * 4];
            const float4 b0 = *(const float4*)&Bs[kk][tx * 4];
            const float4 b1 = *(const float4*)&Bs[kk][64 + tx * 4];
            const float av[8] = {a0.x, a0.y, a0.z, a0.w, a1.x, a1.y, a1.z, a1.w};
            const float bv[8] = {b0.x, b0.y, b0.z, b0.w, b1.x, b1.y, b1.z, b1.w};
#pragma unroll
            for (int i = 0; i < 8; ++i)
#pragma unroll
                for (int j = 0; j < 8; ++j) acc[i][j] += av[i] * bv[j];
        }
        __syncthreads();
    }

#pragma unroll
    for (int i = 0; i < 8; ++i) {
        int lrow = (i < 4) ? (ty * 4 + i) : (64 + ty * 4 + i - 4);
        bool zero = (stok[lrow] < 0);
        size_t rbase = (size_t)(bm + lrow) * DDIM + bn;
        float4 o0, o1;
        float* p0 = &o0.x;
        float* p1 = &o1.x;
#pragma unroll
        for (int j = 0; j < 4; ++j) {
            float v0 = acc[i][j] + bias[bn + tx * 4 + j];
            float v1 = acc[i][j + 4] + bias[bn + 64 + tx * 4 + j];
            p0[j] = zero ? 0.f : v0;
            p1[j] = zero ? 0.f : v1;
        }
        *(float4*)&C[rbase + tx * 4] = o0;
        *(float4*)&C[rbase + 64 + tx * 4] = o1;
    }
}

// ---------------- em GEMMs: 64x64 tile, 4x4 micro, split-K, writes partials ----------------
template <int KCHUNK>
__global__ __launch_bounds__(256) void gemm64_split(const float* __restrict__ A,
                                                    const float* __restrict__ W,
                                                    float* __restrict__ P) {
    constexpr int BK = 16;
    __shared__ float As[BK][68];
    __shared__ float Bs[BK][64];

    const int tid = threadIdx.x;
    const int bm = blockIdx.x * 64;
    const int bn = blockIdx.y * 64;
    const int kbase = blockIdx.z * KCHUNK;

    const int arow = tid >> 4, ak = tid & 15;
    const int bcol = tid & 63, bk0 = tid >> 6;
    const int ty = tid >> 4, tx = tid & 15;

    float acc[4][4] = {};

    for (int kt = 0; kt < KCHUNK / BK; ++kt) {
        const int k0 = kbase + kt * BK;
#pragma unroll
        for (int e = 0; e < 4; ++e) {
            int row = arow + e * 16;
            As[ak][row] = A[(size_t)(bm + row) * DDIM + k0 + ak];
            int kb = bk0 + e * 4;
            Bs[kb][bcol] = W[(size_t)(k0 + kb) * DDIM + bn + bcol];
        }
        __syncthreads();
#pragma unroll
        for (int kk = 0; kk < BK; ++kk) {
            const float4 a4 = *(const float4*)&As[kk][ty * 4];
            const float4 b4 = *(const float4*)&Bs[kk][tx * 4];
            const float av[4] = {a4.x, a4.y, a4.z, a4.w};
            const float bv[4] = {b4.x, b4.y, b4.z, b4.w};
#pragma unroll
            for (int i = 0; i < 4; ++i)
#pragma unroll
                for (int j = 0; j < 4; ++j) acc[i][j] += av[i] * bv[j];
        }
        __syncthreads();
    }

    float* Pd = P + (size_t)blockIdx.z * FELEM;
#pragma unroll
    for (int i = 0; i < 4; ++i) {
        float4 o = {acc[i][0], acc[i][1], acc[i][2], acc[i][3]};
        *(float4*)&Pd[(size_t)(bm + ty * 4 + i) * DDIM + bn + tx * 4] = o;
    }
}

__global__ void em_epi(const float* __restrict__ P, const float* __restrict__ bias,
                       float* __restrict__ out, int relu, int nsplit) {
    int i = blockIdx.x * 256 + threadIdx.x;
    if (i >= FELEM) return;
    float s = 0.f;
    for (int k = 0; k < nsplit; ++k) s += P[(size_t)k * FELEM + i];
    float val = s + bias[i & (DDIM - 1)];
    if (relu) val = fmaxf(val, 0.f);
    out[i] = val;
}

// ---------------- block reductions (256 threads = 4 waves) ----------------
__device__ inline float bred_sum(float x, float* sbuf) {
#pragma unroll
    for (int off = 32; off; off >>= 1) x += __shfl_down(x, off);
    __syncthreads();
    if ((threadIdx.x & 63) == 0) sbuf[threadIdx.x >> 6] = x;
    __syncthreads();
    return sbuf[0] + sbuf[1] + sbuf[2] + sbuf[3];
}
__device__ inline float bred_max(float x, float* sbuf) {
#pragma unroll
    for (int off = 32; off; off >>= 1) x = fmaxf(x, __shfl_down(x, off));
    __syncthreads();
    if ((threadIdx.x & 63) == 0) sbuf[threadIdx.x >> 6] = x;
    __syncthreads();
    return fmaxf(fmaxf(sbuf[0], sbuf[1]), fmaxf(sbuf[2], sbuf[3]));
}

// ---------------- rowops: softmax(S2), l2norm(Tr) -> u, v; inv norms of r,t ----------------
__global__ __launch_bounds__(256) void rowops(const float* __restrict__ S2,
                                              const float* __restrict__ Tr,
                                              const float* __restrict__ rr,
                                              const float* __restrict__ tt,
                                              float* __restrict__ u, float* __restrict__ v,
                                              float* __restrict__ inv_r,
                                              float* __restrict__ inv_t) {
    __shared__ float sbuf[4];
    const int b = blockIdx.x, tid = threadIdx.x;
    const size_t base = (size_t)b * DDIM + tid * 4;

    const float4 s4 = *(const float4*)&S2[base];
    float mx = fmaxf(fmaxf(s4.x, s4.y), fmaxf(s4.z, s4.w));
    mx = bred_max(mx, sbuf);
    float e0 = expf(s4.x - mx), e1 = expf(s4.y - mx), e2 = expf(s4.z - mx), e3 = expf(s4.w - mx);
    float sum = bred_sum(e0 + e1 + e2 + e3, sbuf);
    float invsum = 1.f / sum;

    const float4 tr4 = *(const float4*)&Tr[base];
    float ss = tr4.x * tr4.x + tr4.y * tr4.y + tr4.z * tr4.z + tr4.w * tr4.w;
    ss = bred_sum(ss, sbuf);
    float invn = 1.f / sqrtf(ss);

    float a0 = e0 * invsum, a1 = e1 * invsum, a2 = e2 * invsum, a3 = e3 * invsum;
    float4 u4, v4;
    u4.x = tr4.x * invn * a0; u4.y = tr4.y * invn * a1;
    u4.z = tr4.z * invn * a2; u4.w = tr4.w * invn * a3;
    v4.x = a0 * a0; v4.y = a1 * a1; v4.z = a2 * a2; v4.w = a3 * a3;
    *(float4*)&u[base] = u4;
    *(float4*)&v[base] = v4;

    const float4 r4 = *(const float4*)&rr[base];
    float sr = bred_sum(r4.x * r4.x + r4.y * r4.y + r4.z * r4.z + r4.w * r4.w, sbuf);
    const float4 t4 = *(const float4*)&tt[base];
    float st = bred_sum(t4.x * t4.x + t4.y * t4.y + t4.z * t4.z + t4.w * t4.w, sbuf);
    if (tid == 0) {
        inv_r[b] = 1.f / sqrtf(sr);
        inv_t[b] = 1.f / sqrtf(st);
    }
}

// ---------------- score partials: 32x32 tile, 2x2 micro, split-K ----------------
template <int KCHUNK>
__global__ __launch_bounds__(256) void score_part(const float* __restrict__ u,
                                                  const float* __restrict__ v,
                                                  const float* __restrict__ rr,
                                                  const float* __restrict__ tt,
                                                  float* __restrict__ sp) {
    constexpr int NSPLIT = DDIM / KCHUNK;
    __shared__ float Us[16][36], Vs[16][36], Rs[16][36], Ts[16][36];

    const int tid = threadIdx.x;
    const int bm = blockIdx.x * 32, bn = blockIdx.y * 32;
    const int s = blockIdx.z;
    const int kbase = s * KCHUNK;
    const int lrow0 = tid >> 4, lk = tid & 15;
    const int ty = tid >> 4, tx = tid & 15;

    float a1[2][2] = {}, a2[2][2] = {}, a3[2][2] = {};

    for (int kt = 0; kt < KCHUNK / 16; ++kt) {
        const int k0 = kbase + kt * 16;
#pragma unroll
        for (int e = 0; e < 2; ++e) {
            int row = lrow0 + e * 16;
            Us[lk][row] = u[(size_t)(bm + row) * DDIM + k0 + lk];
            Vs[lk][row] = v[(size_t)(bm + row) * DDIM + k0 + lk];
            Rs[lk][row] = rr[(size_t)(bm + row) * DDIM + k0 + lk];
            Ts[lk][row] = tt[(size_t)(bn + row) * DDIM + k0 + lk];
        }
        __syncthreads();
#pragma unroll
        for (int kk = 0; kk < 16; ++kk) {
            const float2 uu = *(const float2*)&Us[kk][ty * 2];
            const float2 vv = *(const float2*)&Vs[kk][ty * 2];
            const float2 rv = *(const float2*)&Rs[kk][ty * 2];
            const float2 tv = *(const float2*)&Ts[kk][tx * 2];
            const float t2x = tv.x * tv.x, t2y = tv.y * tv.y;
            a1[0][0] += uu.x * tv.x; a1[0][1] += uu.x * tv.y;
            a1[1][0] += uu.y * tv.x; a1[1][1] += uu.y * tv.y;
            a2[0][0] += vv.x * t2x;  a2[0][1] += vv.x * t2y;
            a2[1][0] += vv.y * t2x;  a2[1][1] += vv.y * t2y;
            a3[0][0] += rv.x * tv.x; a3[0][1] += rv.x * tv.y;
            a3[1][0] += rv.y * tv.x; a3[1][1] += rv.y * tv.y;
        }
        __syncthreads();
    }

#pragma unroll
    for (int i = 0; i < 2; ++i)
#pragma unroll
        for (int j = 0; j < 2; ++j) {
            int idx = (bm + ty * 2 + i) * BDIM + bn + tx * 2 + j;
            sp[(size_t)(0 * NSPLIT + s) * SELEM + idx] = a1[i][j];
            sp[(size_t)(1 * NSPLIT + s) * SELEM + idx] = a2[i][j];
            sp[(size_t)(2 * NSPLIT + s) * SELEM + idx] = a3[i][j];
        }
}

__global__ void score_epi(const float* __restrict__ sp, const float* __restrict__ inv_r,
                          const float* __restrict__ inv_t, float* __restrict__ out,
                          int nsplit) {
    int i = blockIdx.x * 256 + threadIdx.x;
    if (i >= SELEM) return;
    float s1 = 0.f, s2 = 0.f, s3 = 0.f;
    for (int k = 0; k < nsplit; ++k) {
        s1 += sp[(size_t)(0 * nsplit + k) * SELEM + i];
        s2 += sp[(size_t)(1 * nsplit + k) * SELEM + i];
        s3 += sp[(size_t)(2 * nsplit + k) * SELEM + i];
    }
    int row = i / BDIM, col = i - row * BDIM;
    out[i] = s1 / sqrtf(s2) + s3 * inv_r[row] * inv_t[col];
}

extern "C" void kernel_launch(void* const* d_in, const int* in_sizes, int n_in, void* d_out,
                              int out_size, void* d_ws, size_t ws_size, hipStream_t stream) {
    const float* r = (const float*)d_in[0];
    const float* m = (const float*)d_in[1];
    const float* t = (const float*)d_in[2];
    const int* ntid = (const int*)d_in[3];
    const int* nlen = (const int*)d_in[4];
    const int* ant = (const int*)d_in[5];
    const float* embed = (const float*)d_in[6];
    const float* noun_W = (const float*)d_in[7];
    const float* noun_b = (const float*)d_in[8];
    const float* em_W1 = (const float*)d_in[9];
    const float* em_b1 = (const float*)d_in[10];
    const float* em_W2 = (const float*)d_in[11];
    const float* em_b2 = (const float*)d_in[12];
    const float* tr_W = (const float*)d_in[13];
    const float* tr_b = (const float*)d_in[14];
    const int* t2i = (const int*)d_in[15];

    float* score = (float*)d_out;
    float* concepts = score + (size_t)SELEM;

    const size_t F = FELEM;
    // Big layout: rowtok/inv (8192 floats) + h,S2,Tr,u,v (5F) + P (4F) + SP (12*SELEM)
    const size_t big_need = (8192 + 9 * F + 12 * (size_t)SELEM) * sizeof(float);
    const bool big = ws_size >= big_need;

    float* fbase = (float*)d_ws;
    int* rowtok = (int*)d_ws;            // 6144 ints
    float* inv_r = fbase + 6144;         // 384
    float* inv_t = inv_r + 384;          // 384
    float* A0 = fbase + 8192;
    float* h = A0;
    float* S2 = A0 + F;
    float* Tr = A0 + 2 * F;
    float* B0 = A0 + 3 * F;
    float* u = B0;
    float* v = B0 + F;
    // small path: P aliases u,v (2F, dead before rowops); SP aliases h/S2/Tr (dead after rowops)
    float* P  = big ? (B0 + 2 * F) : B0;
    float* SP = big ? (B0 + 6 * F) : A0;
    const int ES = big ? 4 : 2;  // em split
    const int SS = big ? 4 : 2;  // score split

    tok_kernel<<<(NROWS + 255) / 256, 256, 0, stream>>>(ntid, nlen, ant, t2i, rowtok);

    dim3 gC(NROWS / 128, DDIM / 128);  // 48 x 8
    gemm128_gather<<<gC, 256, 0, stream>>>(embed, rowtok, noun_W, noun_b, concepts);

    dim3 gE(BDIM / 64, DDIM / 64, ES);  // 6 x 16 x ES
    dim3 gEpi((FELEM + 255) / 256);
    if (big) {
        gemm64_split<256><<<gE, 256, 0, stream>>>(m, em_W1, P);
        em_epi<<<gEpi, 256, 0, stream>>>(P, em_b1, h, 1, ES);
        gemm64_split<256><<<gE, 256, 0, stream>>>(h, em_W2, P);
        em_epi<<<gEpi, 256, 0, stream>>>(P, em_b2, S2, 0, ES);
        gemm64_split<256><<<gE, 256, 0, stream>>>(m, tr_W, P);
        em_epi<<<gEpi, 256, 0, stream>>>(P, tr_b, Tr, 0, ES);
    } else {
        gemm64_split<512><<<gE, 256, 0, stream>>>(m, em_W1, P);
        em_epi<<<gEpi, 256, 0, stream>>>(P, em_b1, h, 1, ES);
        gemm64_split<512><<<gE, 256, 0, stream>>>(h, em_W2, P);
        em_epi<<<gEpi, 256, 0, stream>>>(P, em_b2, S2, 0, ES);
        gemm64_split<512><<<gE, 256, 0, stream>>>(m, tr_W, P);
        em_epi<<<gEpi, 256, 0, stream>>>(P, tr_b, Tr, 0, ES);
    }

    rowops<<<BDIM, 256, 0, stream>>>(S2, Tr, r, t, u, v, inv_r, inv_t);

    dim3 gS(BDIM / 32, BDIM / 32, SS);  // 12 x 12 x SS
    if (big)
        score_part<256><<<gS, 256, 0, stream>>>(u, v, r, t, SP);
    else
        score_part<512><<<gS, 256, 0, stream>>>(u, v, r, t, SP);

    dim3 gSE((SELEM + 255) / 256);
    score_epi<<<gSE, 256, 0, stream>>>(SP, inv_r, inv_t, score, SS);
}

// Round 3
// 137.106 us; speedup vs baseline: 2.5900x; 1.5557x over previous
//
#include <hip/hip_runtime.h>
#include <hip/hip_bf16.h>

#define BDIM 384
#define DDIM 1024
#define LDIM 16
#define WD 300
#define CK 320                 // K padded to 32-multiple for MFMA
#define NROWS (BDIM * LDIM)    // 6144
#define FELEM (BDIM * DDIM)    // 393216
#define SELEM (BDIM * BDIM)    // 147456

typedef __attribute__((ext_vector_type(8))) short short8v;   // 8 bf16 (4 VGPRs)
typedef __attribute__((ext_vector_type(4))) float f32x4;

__device__ inline ushort f2bf(float x) {
    union { float f; unsigned u; } c; c.f = x;
    unsigned u = c.u;
    unsigned r = (u + 0x7fffu + ((u >> 16) & 1u)) >> 16;   // RNE
    return (ushort)r;
}

// ---------------- tok resolve: tok_eff per (b,l) row, -1 if invalid ----------------
__global__ void tok_kernel(const int* __restrict__ ntid, const int* __restrict__ nlen,
                           const int* __restrict__ ant, const int* __restrict__ t2i,
                           int* __restrict__ rowtok) {
    int i = blockIdx.x * 256 + threadIdx.x;
    if (i >= NROWS) return;
    int b = i >> 4, l = i & 15;
    int tok = ntid[i];
    int w = t2i[tok];
    int eff = (w > 0) ? ant[w] : tok;   // `if weight_idx:` falsy-0 semantics
    rowtok[i] = (l < nlen[b]) ? eff : -1;
}

// ---------------- prepass A: gather embed rows -> bf16 [NROWS][CK], zero pad/invalid ----
__global__ __launch_bounds__(256) void prepA(const float* __restrict__ embed,
                                             const int* __restrict__ rowtok,
                                             ushort* __restrict__ Abf) {
    int idx = blockIdx.x * 256 + threadIdx.x;   // NROWS*80 units of 4 k-elems
    if (idx >= NROWS * (CK / 4)) return;
    int row = idx / (CK / 4);
    int q = idx - row * (CK / 4);
    int tok = rowtok[row];
    ushort4 o = {0, 0, 0, 0};
    if (tok >= 0 && q < WD / 4) {   // WD=300 divisible by 4; rows start 16B-aligned (1200B)
        float4 v = *(const float4*)&embed[(size_t)tok * WD + q * 4];
        o.x = f2bf(v.x); o.y = f2bf(v.y); o.z = f2bf(v.z); o.w = f2bf(v.w);
    }
    *(ushort4*)&Abf[(size_t)row * CK + q * 4] = o;
}

// ---------------- prepass B: transpose noun_W [300][1024] -> bf16 [1024][CK] -----------
__global__ __launch_bounds__(256) void prepB(const float* __restrict__ W,
                                             ushort* __restrict__ BT) {
    __shared__ float tile[32][33];
    const int k0 = blockIdx.x * 32;   // 10 k-tiles cover CK=320
    const int c0 = blockIdx.y * 32;
    const int t = threadIdx.x;
    const int r = t >> 3, q = t & 7;
    int k = k0 + r;
    float4 v = {0, 0, 0, 0};
    if (k < WD) v = *(const float4*)&W[(size_t)k * DDIM + c0 + q * 4];
    tile[r][q * 4 + 0] = v.x; tile[r][q * 4 + 1] = v.y;
    tile[r][q * 4 + 2] = v.z; tile[r][q * 4 + 3] = v.w;
    __syncthreads();
    ushort4 o;
    o.x = f2bf(tile[q * 4 + 0][r]);
    o.y = f2bf(tile[q * 4 + 1][r]);
    o.z = f2bf(tile[q * 4 + 2][r]);
    o.w = f2bf(tile[q * 4 + 3][r]);
    *(ushort4*)&BT[(size_t)(c0 + r) * CK + k0 + q * 4] = o;
}

// ---------------- concepts: 128x128 MFMA bf16 GEMM, K=CK ----------------
// LDS tiles K-contiguous, padded row stride 40 shorts (80B): b128 bank-quad =
// (row*5+g) mod 8, 5 coprime 8 -> conflict-free reads AND writes.
__global__ __launch_bounds__(256) void concepts_mfma(const ushort* __restrict__ Abf,
                                                     const ushort* __restrict__ BbfT,
                                                     const int* __restrict__ rowtok,
                                                     const float* __restrict__ bias,
                                                     float* __restrict__ C) {
    __shared__ __align__(16) ushort As[128 * 40];
    __shared__ __align__(16) ushort Bs[128 * 40];
    __shared__ int stok[128];

    const int tid = threadIdx.x;
    const int bm = blockIdx.x * 128, bn = blockIdx.y * 128;
    if (tid < 128) stok[tid] = rowtok[bm + tid];

    const int w = tid >> 6, lane = tid & 63;
    const int wrow = (w & 1) * 64, wcol = (w >> 1) * 64;
    const int frow = lane & 15, fk = lane >> 4;   // fragment row/col idx, k-group

    f32x4 acc[4][4];
#pragma unroll
    for (int i = 0; i < 4; ++i)
#pragma unroll
        for (int j = 0; j < 4; ++j) acc[i][j] = (f32x4){0.f, 0.f, 0.f, 0.f};

    const int srow = tid >> 2, spart = tid & 3;   // staging: 4 chunks of 16B per thread

    for (int ks = 0; ks < CK / 32; ++ks) {
        const int k0 = ks * 32;
        // stage A rows 0..127 (it=0,1) and B cols 0..127 (it=2,3); uniform branch per it
        {
            const ushort* s0 = &Abf[(size_t)(bm + srow) * CK + k0 + spart * 8];
            *(int4*)&As[srow * 40 + spart * 8] = *(const int4*)s0;
            const ushort* s1 = &Abf[(size_t)(bm + 64 + srow) * CK + k0 + spart * 8];
            *(int4*)&As[(64 + srow) * 40 + spart * 8] = *(const int4*)s1;
            const ushort* s2 = &BbfT[(size_t)(bn + srow) * CK + k0 + spart * 8];
            *(int4*)&Bs[srow * 40 + spart * 8] = *(const int4*)s2;
            const ushort* s3 = &BbfT[(size_t)(bn + 64 + srow) * CK + k0 + spart * 8];
            *(int4*)&Bs[(64 + srow) * 40 + spart * 8] = *(const int4*)s3;
        }
        __syncthreads();
        short8v a[4], b[4];
#pragma unroll
        for (int i = 0; i < 4; ++i)
            a[i] = *(const short8v*)&As[(wrow + i * 16 + frow) * 40 + fk * 8];
#pragma unroll
        for (int j = 0; j < 4; ++j)
            b[j] = *(const short8v*)&Bs[(wcol + j * 16 + frow) * 40 + fk * 8];
#pragma unroll
        for (int i = 0; i < 4; ++i)
#pragma unroll
            for (int j = 0; j < 4; ++j)
                acc[i][j] = __builtin_amdgcn_mfma_f32_16x16x32_bf16(a[i], b[j], acc[i][j], 0, 0, 0);
        __syncthreads();
    }

#pragma unroll
    for (int i = 0; i < 4; ++i) {
#pragma unroll
        for (int r = 0; r < 4; ++r) {
            int lrow = wrow + i * 16 + fk * 4 + r;
            bool zero = (stok[lrow] < 0);
            size_t rb = (size_t)(bm + lrow) * DDIM + bn;
#pragma unroll
            for (int j = 0; j < 4; ++j) {
                int lcol = wcol + j * 16 + frow;
                float vv = acc[i][j][r] + bias[bn + lcol];
                C[rb + lcol] = zero ? 0.f : vv;
            }
        }
    }
}

// ---------------- em GEMMs: 64x64 tile, 4x4 micro, split-K, writes partials ----------------
template <int KCHUNK>
__global__ __launch_bounds__(256) void gemm64_split(const float* __restrict__ A,
                                                    const float* __restrict__ W,
                                                    float* __restrict__ P) {
    constexpr int BK = 16;
    __shared__ float As[BK][68];
    __shared__ float Bs[BK][64];

    const int tid = threadIdx.x;
    const int bm = blockIdx.x * 64;
    const int bn = blockIdx.y * 64;
    const int kbase = blockIdx.z * KCHUNK;

    const int arow = tid >> 4, ak = tid & 15;
    const int bcol = tid & 63, bk0 = tid >> 6;
    const int ty = tid >> 4, tx = tid & 15;

    float acc[4][4] = {};

    for (int kt = 0; kt < KCHUNK / BK; ++kt) {
        const int k0 = kbase + kt * BK;
#pragma unroll
        for (int e = 0; e < 4; ++e) {
            int row = arow + e * 16;
            As[ak][row] = A[(size_t)(bm + row) * DDIM + k0 + ak];
            int kb = bk0 + e * 4;
            Bs[kb][bcol] = W[(size_t)(k0 + kb) * DDIM + bn + bcol];
        }
        __syncthreads();
#pragma unroll
        for (int kk = 0; kk < BK; ++kk) {
            const float4 a4 = *(const float4*)&As[kk][ty * 4];
            const float4 b4 = *(const float4*)&Bs[kk][tx * 4];
            const float av[4] = {a4.x, a4.y, a4.z, a4.w};
            const float bv[4] = {b4.x, b4.y, b4.z, b4.w};
#pragma unroll
            for (int i = 0; i < 4; ++i)
#pragma unroll
                for (int j = 0; j < 4; ++j) acc[i][j] += av[i] * bv[j];
        }
        __syncthreads();
    }

    float* Pd = P + (size_t)blockIdx.z * FELEM;
#pragma unroll
    for (int i = 0; i < 4; ++i) {
        float4 o = {acc[i][0], acc[i][1], acc[i][2], acc[i][3]};
        *(float4*)&Pd[(size_t)(bm + ty * 4 + i) * DDIM + bn + tx * 4] = o;
    }
}

__global__ void em_epi(const float* __restrict__ P, const float* __restrict__ bias,
                       float* __restrict__ out, int relu, int nsplit) {
    int i = blockIdx.x * 256 + threadIdx.x;
    if (i >= FELEM) return;
    float s = 0.f;
    for (int k = 0; k < nsplit; ++k) s += P[(size_t)k * FELEM + i];
    float val = s + bias[i & (DDIM - 1)];
    if (relu) val = fmaxf(val, 0.f);
    out[i] = val;
}

// ---------------- block reductions (256 threads = 4 waves) ----------------
__device__ inline float bred_sum(float x, float* sbuf) {
#pragma unroll
    for (int off = 32; off; off >>= 1) x += __shfl_down(x, off);
    __syncthreads();
    if ((threadIdx.x & 63) == 0) sbuf[threadIdx.x >> 6] = x;
    __syncthreads();
    return sbuf[0] + sbuf[1] + sbuf[2] + sbuf[3];
}
__device__ inline float bred_max(float x, float* sbuf) {
#pragma unroll
    for (int off = 32; off; off >>= 1) x = fmaxf(x, __shfl_down(x, off));
    __syncthreads();
    if ((threadIdx.x & 63) == 0) sbuf[threadIdx.x >> 6] = x;
    __syncthreads();
    return fmaxf(fmaxf(sbuf[0], sbuf[1]), fmaxf(sbuf[2], sbuf[3]));
}

// ---------------- rowops: softmax(S2), l2norm(Tr) -> u, v; inv norms of r,t ----------------
__global__ __launch_bounds__(256) void rowops(const float* __restrict__ S2,
                                              const float* __restrict__ Tr,
                                              const float* __restrict__ rr,
                                              const float* __restrict__ tt,
                                              float* __restrict__ u, float* __restrict__ v,
                                              float* __restrict__ inv_r,
                                              float* __restrict__ inv_t) {
    __shared__ float sbuf[4];
    const int b = blockIdx.x, tid = threadIdx.x;
    const size_t base = (size_t)b * DDIM + tid * 4;

    const float4 s4 = *(const float4*)&S2[base];
    float mx = fmaxf(fmaxf(s4.x, s4.y), fmaxf(s4.z, s4.w));
    mx = bred_max(mx, sbuf);
    float e0 = expf(s4.x - mx), e1 = expf(s4.y - mx), e2 = expf(s4.z - mx), e3 = expf(s4.w - mx);
    float sum = bred_sum(e0 + e1 + e2 + e3, sbuf);
    float invsum = 1.f / sum;

    const float4 tr4 = *(const float4*)&Tr[base];
    float ss = tr4.x * tr4.x + tr4.y * tr4.y + tr4.z * tr4.z + tr4.w * tr4.w;
    ss = bred_sum(ss, sbuf);
    float invn = 1.f / sqrtf(ss);

    float a0 = e0 * invsum, a1 = e1 * invsum, a2 = e2 * invsum, a3 = e3 * invsum;
    float4 u4, v4;
    u4.x = tr4.x * invn * a0; u4.y = tr4.y * invn * a1;
    u4.z = tr4.z * invn * a2; u4.w = tr4.w * invn * a3;
    v4.x = a0 * a0; v4.y = a1 * a1; v4.z = a2 * a2; v4.w = a3 * a3;
    *(float4*)&u[base] = u4;
    *(float4*)&v[base] = v4;

    const float4 r4 = *(const float4*)&rr[base];
    float sr = bred_sum(r4.x * r4.x + r4.y * r4.y + r4.z * r4.z + r4.w * r4.w, sbuf);
    const float4 t4 = *(const float4*)&tt[base];
    float st = bred_sum(t4.x * t4.x + t4.y * t4.y + t4.z * t4.z + t4.w * t4.w, sbuf);
    if (tid == 0) {
        inv_r[b] = 1.f / sqrtf(sr);
        inv_t[b] = 1.f / sqrtf(st);
    }
}

// ---------------- score partials: 32x32 tile, 2x2 micro, split-K ----------------
template <int KCHUNK>
__global__ __launch_bounds__(256) void score_part(const float* __restrict__ u,
                                                  const float* __restrict__ v,
                                                  const float* __restrict__ rr,
                                                  const float* __restrict__ tt,
                                                  float* __restrict__ sp) {
    constexpr int NSPLIT = DDIM / KCHUNK;
    __shared__ float Us[16][36], Vs[16][36], Rs[16][36], Ts[16][36];

    const int tid = threadIdx.x;
    const int bm = blockIdx.x * 32, bn = blockIdx.y * 32;
    const int s = blockIdx.z;
    const int kbase = s * KCHUNK;
    const int lrow0 = tid >> 4, lk = tid & 15;
    const int ty = tid >> 4, tx = tid & 15;

    float a1[2][2] = {}, a2[2][2] = {}, a3[2][2] = {};

    for (int kt = 0; kt < KCHUNK / 16; ++kt) {
        const int k0 = kbase + kt * 16;
#pragma unroll
        for (int e = 0; e < 2; ++e) {
            int row = lrow0 + e * 16;
            Us[lk][row] = u[(size_t)(bm + row) * DDIM + k0 + lk];
            Vs[lk][row] = v[(size_t)(bm + row) * DDIM + k0 + lk];
            Rs[lk][row] = rr[(size_t)(bm + row) * DDIM + k0 + lk];
            Ts[lk][row] = tt[(size_t)(bn + row) * DDIM + k0 + lk];
        }
        __syncthreads();
#pragma unroll
        for (int kk = 0; kk < 16; ++kk) {
            const float2 uu = *(const float2*)&Us[kk][ty * 2];
            const float2 vv = *(const float2*)&Vs[kk][ty * 2];
            const float2 rv = *(const float2*)&Rs[kk][ty * 2];
            const float2 tv = *(const float2*)&Ts[kk][tx * 2];
            const float t2x = tv.x * tv.x, t2y = tv.y * tv.y;
            a1[0][0] += uu.x * tv.x; a1[0][1] += uu.x * tv.y;
            a1[1][0] += uu.y * tv.x; a1[1][1] += uu.y * tv.y;
            a2[0][0] += vv.x * t2x;  a2[0][1] += vv.x * t2y;
            a2[1][0] += vv.y * t2x;  a2[1][1] += vv.y * t2y;
            a3[0][0] += rv.x * tv.x; a3[0][1] += rv.x * tv.y;
            a3[1][0] += rv.y * tv.x; a3[1][1] += rv.y * tv.y;
        }
        __syncthreads();
    }

#pragma unroll
    for (int i = 0; i < 2; ++i)
#pragma unroll
        for (int j = 0; j < 2; ++j) {
            int idx = (bm + ty * 2 + i) * BDIM + bn + tx * 2 + j;
            sp[(size_t)(0 * NSPLIT + s) * SELEM + idx] = a1[i][j];
            sp[(size_t)(1 * NSPLIT + s) * SELEM + idx] = a2[i][j];
            sp[(size_t)(2 * NSPLIT + s) * SELEM + idx] = a3[i][j];
        }
}

__global__ void score_epi(const float* __restrict__ sp, const float* __restrict__ inv_r,
                          const float* __restrict__ inv_t, float* __restrict__ out,
                          int nsplit) {
    int i = blockIdx.x * 256 + threadIdx.x;
    if (i >= SELEM) return;
    float s1 = 0.f, s2 = 0.f, s3 = 0.f;
    for (int k = 0; k < nsplit; ++k) {
        s1 += sp[(size_t)(0 * nsplit + k) * SELEM + i];
        s2 += sp[(size_t)(1 * nsplit + k) * SELEM + i];
        s3 += sp[(size_t)(2 * nsplit + k) * SELEM + i];
    }
    int row = i / BDIM, col = i - row * BDIM;
    out[i] = s1 / sqrtf(s2) + s3 * inv_r[row] * inv_t[col];
}

extern "C" void kernel_launch(void* const* d_in, const int* in_sizes, int n_in, void* d_out,
                              int out_size, void* d_ws, size_t ws_size, hipStream_t stream) {
    const float* r = (const float*)d_in[0];
    const float* m = (const float*)d_in[1];
    const float* t = (const float*)d_in[2];
    const int* ntid = (const int*)d_in[3];
    const int* nlen = (const int*)d_in[4];
    const int* ant = (const int*)d_in[5];
    const float* embed = (const float*)d_in[6];
    const float* noun_W = (const float*)d_in[7];
    const float* noun_b = (const float*)d_in[8];
    const float* em_W1 = (const float*)d_in[9];
    const float* em_b1 = (const float*)d_in[10];
    const float* em_W2 = (const float*)d_in[11];
    const float* em_b2 = (const float*)d_in[12];
    const float* tr_W = (const float*)d_in[13];
    const float* tr_b = (const float*)d_in[14];
    const int* t2i = (const int*)d_in[15];

    float* score = (float*)d_out;
    float* concepts = score + (size_t)SELEM;

    const size_t F = FELEM;
    const size_t big_need = (8192 + 9 * F + 12 * (size_t)SELEM) * sizeof(float);
    const bool big = ws_size >= big_need;

    float* fbase = (float*)d_ws;
    int* rowtok = (int*)d_ws;            // 6144 ints
    float* inv_r = fbase + 6144;         // 384
    float* inv_t = inv_r + 384;          // 384
    float* A0 = fbase + 8192;
    float* h = A0;
    float* S2 = A0 + F;
    float* Tr = A0 + 2 * F;
    float* B0 = A0 + 3 * F;
    float* u = B0;
    float* v = B0 + F;
    float* P  = big ? (B0 + 2 * F) : B0;   // small: P aliases u,v (dead before rowops)
    float* SP = big ? (B0 + 6 * F) : A0;   // small: SP aliases h/S2/Tr (dead after rowops)
    const int ES = big ? 4 : 2;
    const int SS = big ? 4 : 2;

    // bf16 staging for concepts: big -> in P (4F floats >= 4.59MB); small -> in A0
    // (3F floats = 4.72MB >= (6144+1024)*320 shorts = 4.59MB; h/S2/Tr written later)
    ushort* Abf = (ushort*)(big ? P : A0);
    ushort* BbfT = Abf + (size_t)NROWS * CK;

    tok_kernel<<<(NROWS + 255) / 256, 256, 0, stream>>>(ntid, nlen, ant, t2i, rowtok);

    prepA<<<(NROWS * (CK / 4) + 255) / 256, 256, 0, stream>>>(embed, rowtok, Abf);
    prepB<<<dim3(CK / 32, DDIM / 32), 256, 0, stream>>>(noun_W, BbfT);

    dim3 gC(NROWS / 128, DDIM / 128);  // 48 x 8
    concepts_mfma<<<gC, 256, 0, stream>>>(Abf, BbfT, rowtok, noun_b, concepts);

    dim3 gE(BDIM / 64, DDIM / 64, ES);  // 6 x 16 x ES
    dim3 gEpi((FELEM + 255) / 256);
    if (big) {
        gemm64_split<256><<<gE, 256, 0, stream>>>(m, em_W1, P);
        em_epi<<<gEpi, 256, 0, stream>>>(P, em_b1, h, 1, ES);
        gemm64_split<256><<<gE, 256, 0, stream>>>(h, em_W2, P);
        em_epi<<<gEpi, 256, 0, stream>>>(P, em_b2, S2, 0, ES);
        gemm64_split<256><<<gE, 256, 0, stream>>>(m, tr_W, P);
        em_epi<<<gEpi, 256, 0, stream>>>(P, tr_b, Tr, 0, ES);
    } else {
        gemm64_split<512><<<gE, 256, 0, stream>>>(m, em_W1, P);
        em_epi<<<gEpi, 256, 0, stream>>>(P, em_b1, h, 1, ES);
        gemm64_split<512><<<gE, 256, 0, stream>>>(h, em_W2, P);
        em_epi<<<gEpi, 256, 0, stream>>>(P, em_b2, S2, 0, ES);
        gemm64_split<512><<<gE, 256, 0, stream>>>(m, tr_W, P);
        em_epi<<<gEpi, 256, 0, stream>>>(P, tr_b, Tr, 0, ES);
    }

    rowops<<<BDIM, 256, 0, stream>>>(S2, Tr, r, t, u, v, inv_r, inv_t);

    dim3 gS(BDIM / 32, BDIM / 32, SS);  // 12 x 12 x SS
    if (big)
        score_part<256><<<gS, 256, 0, stream>>>(u, v, r, t, SP);
    else
        score_part<512><<<gS, 256, 0, stream>>>(u, v, r, t, SP);

    dim3 gSE((SELEM + 255) / 256);
    score_epi<<<gSE, 256, 0, stream>>>(SP, inv_r, inv_t, score, SS);
}

// Round 4
// 102.014 us; speedup vs baseline: 3.4809x; 1.3440x over previous
//
#include <hip/hip_runtime.h>
#include <hip/hip_bf16.h>

#define BDIM 384
#define DDIM 1024
#define LDIM 16
#define WD 300
#define CK 320                 // concepts K padded to 32-multiple for MFMA
#define NROWS (BDIM * LDIM)    // 6144
#define FELEM (BDIM * DDIM)    // 393216
#define SELEM (BDIM * BDIM)    // 147456

typedef __attribute__((ext_vector_type(8))) short short8v;     // 8 bf16
typedef _Float16 half8 __attribute__((ext_vector_type(8)));    // 8 fp16
typedef __attribute__((ext_vector_type(4))) float f32x4;

__device__ inline ushort f2bf(float x) {
    union { float f; unsigned u; } c; c.f = x;
    unsigned u = c.u;
    unsigned r = (u + 0x7fffu + ((u >> 16) & 1u)) >> 16;   // RNE
    return (ushort)r;
}

// ---------------- tok resolve: tok_eff per (b,l) row, -1 if invalid ----------------
__global__ void tok_kernel(const int* __restrict__ ntid, const int* __restrict__ nlen,
                           const int* __restrict__ ant, const int* __restrict__ t2i,
                           int* __restrict__ rowtok) {
    int i = blockIdx.x * 256 + threadIdx.x;
    if (i >= NROWS) return;
    int b = i >> 4, l = i & 15;
    int tok = ntid[i];
    int w = t2i[tok];
    int eff = (w > 0) ? ant[w] : tok;   // `if weight_idx:` falsy-0 semantics
    rowtok[i] = (l < nlen[b]) ? eff : -1;
}

// ---------------- prepass A: gather embed rows -> bf16 [NROWS][CK], zero pad/invalid ----
__global__ __launch_bounds__(256) void prepA(const float* __restrict__ embed,
                                             const int* __restrict__ rowtok,
                                             ushort* __restrict__ Abf) {
    int idx = blockIdx.x * 256 + threadIdx.x;
    if (idx >= NROWS * (CK / 4)) return;
    int row = idx / (CK / 4);
    int q = idx - row * (CK / 4);
    int tok = rowtok[row];
    ushort4 o = {0, 0, 0, 0};
    if (tok >= 0 && q < WD / 4) {
        float4 v = *(const float4*)&embed[(size_t)tok * WD + q * 4];
        o.x = f2bf(v.x); o.y = f2bf(v.y); o.z = f2bf(v.z); o.w = f2bf(v.w);
    }
    *(ushort4*)&Abf[(size_t)row * CK + q * 4] = o;
}

// ---------------- prepass B: transpose noun_W [300][1024] -> bf16 [1024][CK] -----------
__global__ __launch_bounds__(256) void prepB(const float* __restrict__ W,
                                             ushort* __restrict__ BT) {
    __shared__ float tile[32][33];
    const int k0 = blockIdx.x * 32;
    const int c0 = blockIdx.y * 32;
    const int t = threadIdx.x;
    const int r = t >> 3, q = t & 7;
    int k = k0 + r;
    float4 v = {0, 0, 0, 0};
    if (k < WD) v = *(const float4*)&W[(size_t)k * DDIM + c0 + q * 4];
    tile[r][q * 4 + 0] = v.x; tile[r][q * 4 + 1] = v.y;
    tile[r][q * 4 + 2] = v.z; tile[r][q * 4 + 3] = v.w;
    __syncthreads();
    ushort4 o;
    o.x = f2bf(tile[q * 4 + 0][r]);
    o.y = f2bf(tile[q * 4 + 1][r]);
    o.z = f2bf(tile[q * 4 + 2][r]);
    o.w = f2bf(tile[q * 4 + 3][r]);
    *(ushort4*)&BT[(size_t)(c0 + r) * CK + k0 + q * 4] = o;
}

// ---------------- concepts: 128x128 MFMA bf16 GEMM, K=CK (proven round 3) ----------------
__global__ __launch_bounds__(256) void concepts_mfma(const ushort* __restrict__ Abf,
                                                     const ushort* __restrict__ BbfT,
                                                     const int* __restrict__ rowtok,
                                                     const float* __restrict__ bias,
                                                     float* __restrict__ C) {
    __shared__ __align__(16) ushort As[128 * 40];
    __shared__ __align__(16) ushort Bs[128 * 40];
    __shared__ int stok[128];

    const int tid = threadIdx.x;
    const int bm = blockIdx.x * 128, bn = blockIdx.y * 128;
    if (tid < 128) stok[tid] = rowtok[bm + tid];

    const int w = tid >> 6, lane = tid & 63;
    const int wrow = (w & 1) * 64, wcol = (w >> 1) * 64;
    const int frow = lane & 15, fk = lane >> 4;

    f32x4 acc[4][4];
#pragma unroll
    for (int i = 0; i < 4; ++i)
#pragma unroll
        for (int j = 0; j < 4; ++j) acc[i][j] = (f32x4){0.f, 0.f, 0.f, 0.f};

    const int srow = tid >> 2, spart = tid & 3;

    for (int ks = 0; ks < CK / 32; ++ks) {
        const int k0 = ks * 32;
        {
            const ushort* s0 = &Abf[(size_t)(bm + srow) * CK + k0 + spart * 8];
            *(int4*)&As[srow * 40 + spart * 8] = *(const int4*)s0;
            const ushort* s1 = &Abf[(size_t)(bm + 64 + srow) * CK + k0 + spart * 8];
            *(int4*)&As[(64 + srow) * 40 + spart * 8] = *(const int4*)s1;
            const ushort* s2 = &BbfT[(size_t)(bn + srow) * CK + k0 + spart * 8];
            *(int4*)&Bs[srow * 40 + spart * 8] = *(const int4*)s2;
            const ushort* s3 = &BbfT[(size_t)(bn + 64 + srow) * CK + k0 + spart * 8];
            *(int4*)&Bs[(64 + srow) * 40 + spart * 8] = *(const int4*)s3;
        }
        __syncthreads();
        short8v a[4], b[4];
#pragma unroll
        for (int i = 0; i < 4; ++i)
            a[i] = *(const short8v*)&As[(wrow + i * 16 + frow) * 40 + fk * 8];
#pragma unroll
        for (int j = 0; j < 4; ++j)
            b[j] = *(const short8v*)&Bs[(wcol + j * 16 + frow) * 40 + fk * 8];
#pragma unroll
        for (int i = 0; i < 4; ++i)
#pragma unroll
            for (int j = 0; j < 4; ++j)
                acc[i][j] = __builtin_amdgcn_mfma_f32_16x16x32_bf16(a[i], b[j], acc[i][j], 0, 0, 0);
        __syncthreads();
    }

#pragma unroll
    for (int i = 0; i < 4; ++i) {
#pragma unroll
        for (int r = 0; r < 4; ++r) {
            int lrow = wrow + i * 16 + fk * 4 + r;
            bool zero = (stok[lrow] < 0);
            size_t rb = (size_t)(bm + lrow) * DDIM + bn;
#pragma unroll
            for (int j = 0; j < 4; ++j) {
                int lcol = wcol + j * 16 + frow;
                float vv = acc[i][j][r] + bias[bn + lcol];
                C[rb + lcol] = zero ? 0.f : vv;
            }
        }
    }
}

// ---------------- cvt m -> fp16 ----------------
__global__ void cvt_m(const float* __restrict__ m, _Float16* __restrict__ mh) {
    int i = blockIdx.x * 256 + threadIdx.x;
    if (i >= FELEM / 4) return;
    float4 v = ((const float4*)m)[i];
    union { _Float16 h[4]; ushort4 u; } o;
    o.h[0] = (_Float16)v.x; o.h[1] = (_Float16)v.y;
    o.h[2] = (_Float16)v.z; o.h[3] = (_Float16)v.w;
    ((ushort4*)mh)[i] = o.u;
}

// ---------------- transpose W [1024][1024] f32 -> WT [n][k] fp16 ----------------
__global__ __launch_bounds__(256) void transW(const float* __restrict__ W,
                                              _Float16* __restrict__ WT) {
    __shared__ float tile[32][33];
    const int k0 = blockIdx.x * 32, c0 = blockIdx.y * 32;
    const int t = threadIdx.x;
    const int r = t >> 3, q = t & 7;
    float4 v = *(const float4*)&W[(size_t)(k0 + r) * DDIM + c0 + q * 4];
    tile[r][q * 4 + 0] = v.x; tile[r][q * 4 + 1] = v.y;
    tile[r][q * 4 + 2] = v.z; tile[r][q * 4 + 3] = v.w;
    __syncthreads();
    union { _Float16 h[4]; ushort4 u; } o;
    o.h[0] = (_Float16)tile[q * 4 + 0][r];
    o.h[1] = (_Float16)tile[q * 4 + 1][r];
    o.h[2] = (_Float16)tile[q * 4 + 2][r];
    o.h[3] = (_Float16)tile[q * 4 + 3][r];
    *(ushort4*)&WT[(size_t)(c0 + r) * DDIM + k0 + q * 4] = o.u;
}

// ---------------- em GEMM: fp16 MFMA, 32x32 tile, 128 threads, K=1024 ----------------
// MODE 0: out = acc + bias (fp32); MODE 1: out = fp16(relu(acc + bias))
template <int MODE>
__global__ __launch_bounds__(128) void emgemm(const _Float16* __restrict__ Ah,
                                              const _Float16* __restrict__ WT,
                                              const float* __restrict__ bias,
                                              float* __restrict__ outF,
                                              _Float16* __restrict__ outH) {
    __shared__ __align__(16) _Float16 As[32 * 40];
    __shared__ __align__(16) _Float16 Bs[32 * 40];
    const int tid = threadIdx.x;
    const int bm = blockIdx.x * 32, bn = blockIdx.y * 32;
    const int lane = tid & 63;
    const int wrow = (tid >> 6) * 16;
    const int frow = lane & 15, fk = lane >> 4;
    const int srow = tid >> 2, spart = tid & 3;

    f32x4 acc0 = {0.f, 0.f, 0.f, 0.f}, acc1 = {0.f, 0.f, 0.f, 0.f};

    for (int ks = 0; ks < DDIM / 32; ++ks) {
        const int k0 = ks * 32;
        *(int4*)&As[srow * 40 + spart * 8] =
            *(const int4*)&Ah[(size_t)(bm + srow) * DDIM + k0 + spart * 8];
        *(int4*)&Bs[srow * 40 + spart * 8] =
            *(const int4*)&WT[(size_t)(bn + srow) * DDIM + k0 + spart * 8];
        __syncthreads();
        half8 a = *(const half8*)&As[(wrow + frow) * 40 + fk * 8];
        half8 b0 = *(const half8*)&Bs[frow * 40 + fk * 8];
        half8 b1 = *(const half8*)&Bs[(16 + frow) * 40 + fk * 8];
        acc0 = __builtin_amdgcn_mfma_f32_16x16x32_f16(a, b0, acc0, 0, 0, 0);
        acc1 = __builtin_amdgcn_mfma_f32_16x16x32_f16(a, b1, acc1, 0, 0, 0);
        __syncthreads();
    }

    const int orow0 = bm + wrow + fk * 4;
    const int c0 = bn + frow, c1 = bn + 16 + frow;
    const float b0v = bias[c0], b1v = bias[c1];
#pragma unroll
    for (int r = 0; r < 4; ++r) {
        int row = orow0 + r;
        float v0 = acc0[r] + b0v;
        float v1 = acc1[r] + b1v;
        if (MODE == 1) {
            outH[(size_t)row * DDIM + c0] = (_Float16)fmaxf(v0, 0.f);
            outH[(size_t)row * DDIM + c1] = (_Float16)fmaxf(v1, 0.f);
        } else {
            outF[(size_t)row * DDIM + c0] = v0;
            outF[(size_t)row * DDIM + c1] = v1;
        }
    }
}

// ---------------- block reductions (256 threads = 4 waves) ----------------
__device__ inline float bred_sum(float x, float* sbuf) {
#pragma unroll
    for (int off = 32; off; off >>= 1) x += __shfl_down(x, off);
    __syncthreads();
    if ((threadIdx.x & 63) == 0) sbuf[threadIdx.x >> 6] = x;
    __syncthreads();
    return sbuf[0] + sbuf[1] + sbuf[2] + sbuf[3];
}
__device__ inline float bred_max(float x, float* sbuf) {
#pragma unroll
    for (int off = 32; off; off >>= 1) x = fmaxf(x, __shfl_down(x, off));
    __syncthreads();
    if ((threadIdx.x & 63) == 0) sbuf[threadIdx.x >> 6] = x;
    __syncthreads();
    return fmaxf(fmaxf(sbuf[0], sbuf[1]), fmaxf(sbuf[2], sbuf[3]));
}

// ---------------- rowops: softmax(S2), l2norm(Tr) -> fp16 uh,vh,rh,th,t2h; inv norms ----
// uh = 1024*u, vh = (32*A)^2 = 1024*A^2 (fp16 underflow guard)
__global__ __launch_bounds__(256) void rowops(const float* __restrict__ S2,
                                              const float* __restrict__ Tr,
                                              const float* __restrict__ rr,
                                              const float* __restrict__ tt,
                                              _Float16* __restrict__ uh, _Float16* __restrict__ vh,
                                              _Float16* __restrict__ rh, _Float16* __restrict__ th,
                                              _Float16* __restrict__ t2h,
                                              float* __restrict__ inv_r,
                                              float* __restrict__ inv_t) {
    __shared__ float sbuf[4];
    const int b = blockIdx.x, tid = threadIdx.x;
    const size_t base = (size_t)b * DDIM + tid * 4;

    const float4 s4 = *(const float4*)&S2[base];
    float mx = fmaxf(fmaxf(s4.x, s4.y), fmaxf(s4.z, s4.w));
    mx = bred_max(mx, sbuf);
    float e0 = expf(s4.x - mx), e1 = expf(s4.y - mx), e2 = expf(s4.z - mx), e3 = expf(s4.w - mx);
    float sum = bred_sum(e0 + e1 + e2 + e3, sbuf);
    float invsum = 1.f / sum;

    const float4 tr4 = *(const float4*)&Tr[base];
    float ss = tr4.x * tr4.x + tr4.y * tr4.y + tr4.z * tr4.z + tr4.w * tr4.w;
    ss = bred_sum(ss, sbuf);
    float invn = 1.f / sqrtf(ss);

    float a0 = e0 * invsum, a1 = e1 * invsum, a2 = e2 * invsum, a3 = e3 * invsum;
    union { _Float16 h[4]; ushort4 u; } o;

    // uh = Tr_hat * A * 1024
    o.h[0] = (_Float16)(tr4.x * invn * a0 * 1024.f);
    o.h[1] = (_Float16)(tr4.y * invn * a1 * 1024.f);
    o.h[2] = (_Float16)(tr4.z * invn * a2 * 1024.f);
    o.h[3] = (_Float16)(tr4.w * invn * a3 * 1024.f);
    *(ushort4*)&uh[base] = o.u;

    // vh = (32A)^2
    float q0 = a0 * 32.f, q1 = a1 * 32.f, q2 = a2 * 32.f, q3 = a3 * 32.f;
    o.h[0] = (_Float16)(q0 * q0); o.h[1] = (_Float16)(q1 * q1);
    o.h[2] = (_Float16)(q2 * q2); o.h[3] = (_Float16)(q3 * q3);
    *(ushort4*)&vh[base] = o.u;

    const float4 r4 = *(const float4*)&rr[base];
    o.h[0] = (_Float16)r4.x; o.h[1] = (_Float16)r4.y;
    o.h[2] = (_Float16)r4.z; o.h[3] = (_Float16)r4.w;
    *(ushort4*)&rh[base] = o.u;

    const float4 t4 = *(const float4*)&tt[base];
    o.h[0] = (_Float16)t4.x; o.h[1] = (_Float16)t4.y;
    o.h[2] = (_Float16)t4.z; o.h[3] = (_Float16)t4.w;
    *(ushort4*)&th[base] = o.u;

    o.h[0] = (_Float16)(t4.x * t4.x); o.h[1] = (_Float16)(t4.y * t4.y);
    o.h[2] = (_Float16)(t4.z * t4.z); o.h[3] = (_Float16)(t4.w * t4.w);
    *(ushort4*)&t2h[base] = o.u;

    float sr = bred_sum(r4.x * r4.x + r4.y * r4.y + r4.z * r4.z + r4.w * r4.w, sbuf);
    float st = bred_sum(t4.x * t4.x + t4.y * t4.y + t4.z * t4.z + t4.w * t4.w, sbuf);
    if (tid == 0) {
        inv_r[b] = 1.f / sqrtf(sr);
        inv_t[b] = 1.f / sqrtf(st);
    }
}

// ---------------- score: fp16 MFMA, 3 dot-accs, 32x32 tile, K=1024 ----------------
__global__ __launch_bounds__(128) void score_mfma(const _Float16* __restrict__ uh,
                                                  const _Float16* __restrict__ vh,
                                                  const _Float16* __restrict__ rh,
                                                  const _Float16* __restrict__ th,
                                                  const _Float16* __restrict__ t2h,
                                                  const float* __restrict__ inv_r,
                                                  const float* __restrict__ inv_t,
                                                  float* __restrict__ out) {
    __shared__ __align__(16) _Float16 Us[32 * 40];
    __shared__ __align__(16) _Float16 Vs[32 * 40];
    __shared__ __align__(16) _Float16 Rs[32 * 40];
    __shared__ __align__(16) _Float16 Ts[32 * 40];
    __shared__ __align__(16) _Float16 Qs[32 * 40];

    const int tid = threadIdx.x;
    const int bm = blockIdx.x * 32, bn = blockIdx.y * 32;
    const int lane = tid & 63;
    const int wrow = (tid >> 6) * 16;
    const int frow = lane & 15, fk = lane >> 4;
    const int srow = tid >> 2, spart = tid & 3;

    f32x4 an0 = {0.f, 0.f, 0.f, 0.f}, an1 = an0;
    f32x4 ad0 = an0, ad1 = an0, ai0 = an0, ai1 = an0;

    for (int ks = 0; ks < DDIM / 32; ++ks) {
        const int k0 = ks * 32;
        const size_t mo = (size_t)(bm + srow) * DDIM + k0 + spart * 8;
        const size_t no = (size_t)(bn + srow) * DDIM + k0 + spart * 8;
        const int lo = srow * 40 + spart * 8;
        *(int4*)&Us[lo] = *(const int4*)&uh[mo];
        *(int4*)&Vs[lo] = *(const int4*)&vh[mo];
        *(int4*)&Rs[lo] = *(const int4*)&rh[mo];
        *(int4*)&Ts[lo] = *(const int4*)&th[no];
        *(int4*)&Qs[lo] = *(const int4*)&t2h[no];
        __syncthreads();
        half8 au = *(const half8*)&Us[(wrow + frow) * 40 + fk * 8];
        half8 av = *(const half8*)&Vs[(wrow + frow) * 40 + fk * 8];
        half8 ar = *(const half8*)&Rs[(wrow + frow) * 40 + fk * 8];
        half8 bt0 = *(const half8*)&Ts[frow * 40 + fk * 8];
        half8 bt1 = *(const half8*)&Ts[(16 + frow) * 40 + fk * 8];
        half8 bq0 = *(const half8*)&Qs[frow * 40 + fk * 8];
        half8 bq1 = *(const half8*)&Qs[(16 + frow) * 40 + fk * 8];
        an0 = __builtin_amdgcn_mfma_f32_16x16x32_f16(au, bt0, an0, 0, 0, 0);
        an1 = __builtin_amdgcn_mfma_f32_16x16x32_f16(au, bt1, an1, 0, 0, 0);
        ad0 = __builtin_amdgcn_mfma_f32_16x16x32_f16(av, bq0, ad0, 0, 0, 0);
        ad1 = __builtin_amdgcn_mfma_f32_16x16x32_f16(av, bq1, ad1, 0, 0, 0);
        ai0 = __builtin_amdgcn_mfma_f32_16x16x32_f16(ar, bt0, ai0, 0, 0, 0);
        ai1 = __builtin_amdgcn_mfma_f32_16x16x32_f16(ar, bt1, ai1, 0, 0, 0);
        __syncthreads();
    }

    const int orow0 = bm + wrow + fk * 4;
    const int c0 = bn + frow, c1 = bn + 16 + frow;
    const float it0 = inv_t[c0], it1 = inv_t[c1];
#pragma unroll
    for (int r = 0; r < 4; ++r) {
        int row = orow0 + r;
        float ir = inv_r[row];
        // EM = (accn/1024) / sqrt(accd/1024) = accn / (32*sqrt(accd))
        float em0 = an0[r] / (32.f * sqrtf(ad0[r]));
        float em1 = an1[r] / (32.f * sqrtf(ad1[r]));
        out[(size_t)row * BDIM + c0] = em0 + ai0[r] * ir * it0;
        out[(size_t)row * BDIM + c1] = em1 + ai1[r] * ir * it1;
    }
}

extern "C" void kernel_launch(void* const* d_in, const int* in_sizes, int n_in, void* d_out,
                              int out_size, void* d_ws, size_t ws_size, hipStream_t stream) {
    const float* r = (const float*)d_in[0];
    const float* m = (const float*)d_in[1];
    const float* t = (const float*)d_in[2];
    const int* ntid = (const int*)d_in[3];
    const int* nlen = (const int*)d_in[4];
    const int* ant = (const int*)d_in[5];
    const float* embed = (const float*)d_in[6];
    const float* noun_W = (const float*)d_in[7];
    const float* noun_b = (const float*)d_in[8];
    const float* em_W1 = (const float*)d_in[9];
    const float* em_b1 = (const float*)d_in[10];
    const float* em_W2 = (const float*)d_in[11];
    const float* em_b2 = (const float*)d_in[12];
    const float* tr_W = (const float*)d_in[13];
    const float* tr_b = (const float*)d_in[14];
    const int* t2i = (const int*)d_in[15];

    float* score = (float*)d_out;
    float* concepts = score + (size_t)SELEM;

    // ---- workspace layout (peak 7.41 MB, <= proven 7.9 MB) ----
    char* base = (char*)d_ws;
    int* rowtok = (int*)base;                              // 24576 B
    float* inv_r = (float*)(base + 24576);                 // 1536 B
    float* inv_t = inv_r + 384;
    char* RA = base + 32768;                               // 4,587,520 B region
    // phase 1 (concepts staging):
    ushort* Abf = (ushort*)RA;                             // 6144*320*2
    ushort* BbfT = Abf + (size_t)NROWS * CK;               // 1024*320*2
    // phase 2 (em chain), aliases RA after concepts_mfma:
    _Float16* WT = (_Float16*)RA;                          // 2 MB
    _Float16* mh = (_Float16*)(RA + 2097152);              // 768 KB
    _Float16* hh = (_Float16*)(RA + 2883584);              // 768 KB
    // phase 3 (score operands), aliases RA after gemm3:
    _Float16* uh = (_Float16*)RA;
    _Float16* vh = (_Float16*)(RA + 786432);
    _Float16* rh = (_Float16*)(RA + 1572864);
    _Float16* th = (_Float16*)(RA + 2359296);
    _Float16* t2h = (_Float16*)(RA + 3145728);
    // region B (fp32 em outputs), lives past RA:
    float* S2 = (float*)(base + 4620288);                  // 1.5 MB
    float* Tr = (float*)(base + 6193152);                  // 1.5 MB

    tok_kernel<<<(NROWS + 255) / 256, 256, 0, stream>>>(ntid, nlen, ant, t2i, rowtok);

    prepA<<<(NROWS * (CK / 4) + 255) / 256, 256, 0, stream>>>(embed, rowtok, Abf);
    prepB<<<dim3(CK / 32, DDIM / 32), 256, 0, stream>>>(noun_W, BbfT);

    dim3 gC(NROWS / 128, DDIM / 128);  // 48 x 8
    concepts_mfma<<<gC, 256, 0, stream>>>(Abf, BbfT, rowtok, noun_b, concepts);

    cvt_m<<<(FELEM / 4 + 255) / 256, 256, 0, stream>>>(m, mh);

    dim3 gT(DDIM / 32, DDIM / 32);     // 32 x 32
    dim3 gG(BDIM / 32, DDIM / 32);     // 12 x 32 = 384 blocks
    transW<<<gT, 256, 0, stream>>>(em_W1, WT);
    emgemm<1><<<gG, 128, 0, stream>>>(mh, WT, em_b1, nullptr, hh);
    transW<<<gT, 256, 0, stream>>>(em_W2, WT);
    emgemm<0><<<gG, 128, 0, stream>>>(hh, WT, em_b2, S2, nullptr);
    transW<<<gT, 256, 0, stream>>>(tr_W, WT);
    emgemm<0><<<gG, 128, 0, stream>>>(mh, WT, tr_b, Tr, nullptr);

    rowops<<<BDIM, 256, 0, stream>>>(S2, Tr, r, t, uh, vh, rh, th, t2h, inv_r, inv_t);

    dim3 gS(BDIM / 32, BDIM / 32);     // 12 x 12
    score_mfma<<<gS, 128, 0, stream>>>(uh, vh, rh, th, t2h, inv_r, inv_t, score);
}

// Round 5
// 72.332 us; speedup vs baseline: 4.9094x; 1.4104x over previous
//
#include <hip/hip_runtime.h>
#include <hip/hip_bf16.h>

#define BDIM 384
#define DDIM 1024
#define LDIM 16
#define WD 300
#define CK 320                 // concepts K padded to 32-multiple for MFMA
#define NROWS (BDIM * LDIM)    // 6144
#define FELEM (BDIM * DDIM)    // 393216
#define SELEM (BDIM * BDIM)    // 147456

typedef __attribute__((ext_vector_type(8))) short short8v;     // 8 bf16
typedef _Float16 half8 __attribute__((ext_vector_type(8)));    // 8 fp16
typedef __attribute__((ext_vector_type(4))) float f32x4;

__device__ inline ushort f2bf(float x) {
    union { float f; unsigned u; } c; c.f = x;
    unsigned u = c.u;
    unsigned r = (u + 0x7fffu + ((u >> 16) & 1u)) >> 16;   // RNE
    return (ushort)r;
}

// ---------------- prepA (fused tok-resolve): gather embed -> bf16 [NROWS][CK] ----------
__global__ __launch_bounds__(256) void prepA(const float* __restrict__ embed,
                                             const int* __restrict__ ntid,
                                             const int* __restrict__ nlen,
                                             const int* __restrict__ ant,
                                             const int* __restrict__ t2i,
                                             ushort* __restrict__ Abf,
                                             int* __restrict__ rowtok) {
    int idx = blockIdx.x * 256 + threadIdx.x;
    if (idx >= NROWS * (CK / 4)) return;
    int row = idx / (CK / 4);
    int q = idx - row * (CK / 4);
    int tok = ntid[row];
    int w = t2i[tok];
    int eff = (w > 0) ? ant[w] : tok;            // `if weight_idx:` falsy-0 semantics
    bool valid = (row & 15) < nlen[row >> 4];
    if (q == 0) rowtok[row] = valid ? eff : -1;
    ushort4 o = {0, 0, 0, 0};
    if (valid && q < WD / 4) {
        float4 v = *(const float4*)&embed[(size_t)eff * WD + q * 4];
        o.x = f2bf(v.x); o.y = f2bf(v.y); o.z = f2bf(v.z); o.w = f2bf(v.w);
    }
    *(ushort4*)&Abf[(size_t)row * CK + q * 4] = o;
}

// ---------------- prepB: transpose noun_W [300][1024] -> bf16 [1024][CK] -----------
__global__ __launch_bounds__(256) void prepB(const float* __restrict__ W,
                                             ushort* __restrict__ BT) {
    __shared__ float tile[32][33];
    const int k0 = blockIdx.x * 32;
    const int c0 = blockIdx.y * 32;
    const int t = threadIdx.x;
    const int r = t >> 3, q = t & 7;
    int k = k0 + r;
    float4 v = {0, 0, 0, 0};
    if (k < WD) v = *(const float4*)&W[(size_t)k * DDIM + c0 + q * 4];
    tile[r][q * 4 + 0] = v.x; tile[r][q * 4 + 1] = v.y;
    tile[r][q * 4 + 2] = v.z; tile[r][q * 4 + 3] = v.w;
    __syncthreads();
    ushort4 o;
    o.x = f2bf(tile[q * 4 + 0][r]);
    o.y = f2bf(tile[q * 4 + 1][r]);
    o.z = f2bf(tile[q * 4 + 2][r]);
    o.w = f2bf(tile[q * 4 + 3][r]);
    *(ushort4*)&BT[(size_t)(c0 + r) * CK + k0 + q * 4] = o;
}

// ---------------- concepts: 128x128 MFMA bf16 GEMM, K=CK, double-buffered ----------------
__global__ __launch_bounds__(256) void concepts_mfma(const ushort* __restrict__ Abf,
                                                     const ushort* __restrict__ BbfT,
                                                     const int* __restrict__ rowtok,
                                                     const float* __restrict__ bias,
                                                     float* __restrict__ C) {
    __shared__ __align__(16) ushort As[2][128 * 40];
    __shared__ __align__(16) ushort Bs[2][128 * 40];
    __shared__ int stok[128];

    const int tid = threadIdx.x;
    const int bm = blockIdx.x * 128, bn = blockIdx.y * 128;
    if (tid < 128) stok[tid] = rowtok[bm + tid];

    const int w = tid >> 6, lane = tid & 63;
    const int wrow = (w & 1) * 64, wcol = (w >> 1) * 64;
    const int frow = lane & 15, fk = lane >> 4;
    const int srow = tid >> 2, spart = tid & 3;

    f32x4 acc[4][4];
#pragma unroll
    for (int i = 0; i < 4; ++i)
#pragma unroll
        for (int j = 0; j < 4; ++j) acc[i][j] = (f32x4){0.f, 0.f, 0.f, 0.f};

    int4 pa0, pa1, pb0, pb1;
    constexpr int NK = CK / 32;  // 10

#define C_LOAD(ks)                                                              \
    {                                                                           \
        const int k0_ = (ks) * 32;                                              \
        pa0 = *(const int4*)&Abf[(size_t)(bm + srow) * CK + k0_ + spart * 8];   \
        pa1 = *(const int4*)&Abf[(size_t)(bm + 64 + srow) * CK + k0_ + spart * 8]; \
        pb0 = *(const int4*)&BbfT[(size_t)(bn + srow) * CK + k0_ + spart * 8];  \
        pb1 = *(const int4*)&BbfT[(size_t)(bn + 64 + srow) * CK + k0_ + spart * 8]; \
    }
#define C_STORE(buf)                                                            \
    {                                                                           \
        *(int4*)&As[buf][srow * 40 + spart * 8] = pa0;                          \
        *(int4*)&As[buf][(64 + srow) * 40 + spart * 8] = pa1;                   \
        *(int4*)&Bs[buf][srow * 40 + spart * 8] = pb0;                          \
        *(int4*)&Bs[buf][(64 + srow) * 40 + spart * 8] = pb1;                   \
    }

    C_LOAD(0);
    C_STORE(0);
    __syncthreads();
    int cur = 0;

    for (int ks = 0; ks < NK; ++ks) {
        if (ks + 1 < NK) C_LOAD(ks + 1);
        short8v a[4], b[4];
#pragma unroll
        for (int i = 0; i < 4; ++i)
            a[i] = *(const short8v*)&As[cur][(wrow + i * 16 + frow) * 40 + fk * 8];
#pragma unroll
        for (int j = 0; j < 4; ++j)
            b[j] = *(const short8v*)&Bs[cur][(wcol + j * 16 + frow) * 40 + fk * 8];
#pragma unroll
        for (int i = 0; i < 4; ++i)
#pragma unroll
            for (int j = 0; j < 4; ++j)
                acc[i][j] = __builtin_amdgcn_mfma_f32_16x16x32_bf16(a[i], b[j], acc[i][j], 0, 0, 0);
        if (ks + 1 < NK) C_STORE(cur ^ 1);
        __syncthreads();
        cur ^= 1;
    }
#undef C_LOAD
#undef C_STORE

#pragma unroll
    for (int i = 0; i < 4; ++i) {
#pragma unroll
        for (int r = 0; r < 4; ++r) {
            int lrow = wrow + i * 16 + fk * 4 + r;
            bool zero = (stok[lrow] < 0);
            size_t rb = (size_t)(bm + lrow) * DDIM + bn;
#pragma unroll
            for (int j = 0; j < 4; ++j) {
                int lcol = wcol + j * 16 + frow;
                float vv = acc[i][j][r] + bias[bn + lcol];
                C[rb + lcol] = zero ? 0.f : vv;
            }
        }
    }
}

// ---------------- prep_em: z=0..2 transpose W -> fp16 WT[n][k]; z=3: m -> fp16 ----------
__global__ __launch_bounds__(256) void prep_em(const float* __restrict__ W1,
                                               const float* __restrict__ W2,
                                               const float* __restrict__ W3,
                                               _Float16* __restrict__ WT1,
                                               _Float16* __restrict__ WT2,
                                               _Float16* __restrict__ WT3,
                                               const float* __restrict__ m,
                                               _Float16* __restrict__ mh) {
    const int z = blockIdx.z;
    const int t = threadIdx.x;
    if (z == 3) {
        int b = blockIdx.y * 32 + blockIdx.x;
        if (b >= FELEM / 1024) return;
        int i = b * 1024 + t * 4;
        float4 v = *(const float4*)&m[i];
        union { _Float16 h[4]; ushort4 u; } o;
        o.h[0] = (_Float16)v.x; o.h[1] = (_Float16)v.y;
        o.h[2] = (_Float16)v.z; o.h[3] = (_Float16)v.w;
        *(ushort4*)&mh[i] = o.u;
        return;
    }
    const float* W = (z == 0) ? W1 : (z == 1) ? W2 : W3;
    _Float16* WT = (z == 0) ? WT1 : (z == 1) ? WT2 : WT3;
    __shared__ float tile[32][33];
    const int k0 = blockIdx.x * 32, c0 = blockIdx.y * 32;
    const int r = t >> 3, q = t & 7;
    float4 v = *(const float4*)&W[(size_t)(k0 + r) * DDIM + c0 + q * 4];
    tile[r][q * 4 + 0] = v.x; tile[r][q * 4 + 1] = v.y;
    tile[r][q * 4 + 2] = v.z; tile[r][q * 4 + 3] = v.w;
    __syncthreads();
    union { _Float16 h[4]; ushort4 u; } o;
    o.h[0] = (_Float16)tile[q * 4 + 0][r];
    o.h[1] = (_Float16)tile[q * 4 + 1][r];
    o.h[2] = (_Float16)tile[q * 4 + 2][r];
    o.h[3] = (_Float16)tile[q * 4 + 3][r];
    *(ushort4*)&WT[(size_t)(c0 + r) * DDIM + k0 + q * 4] = o.u;
}

// ---------------- em GEMM: fp16 MFMA, 32x32 tile, 128 thr, K-step 64, dbuf ----------------
// MODE 0: out = acc + bias (fp32); MODE 1: out = fp16(relu(acc + bias))
template <int MODE>
__global__ __launch_bounds__(128) void emgemm(const _Float16* __restrict__ Ah,
                                              const _Float16* __restrict__ WT,
                                              const float* __restrict__ bias,
                                              float* __restrict__ outF,
                                              _Float16* __restrict__ outH) {
    __shared__ __align__(16) _Float16 As[2][32 * 72];
    __shared__ __align__(16) _Float16 Bs[2][32 * 72];
    const int tid = threadIdx.x;
    const int bm = blockIdx.x * 32, bn = blockIdx.y * 32;
    const int lane = tid & 63;
    const int wrow = (tid >> 6) * 16;
    const int frow = lane & 15, fk = lane >> 4;
    const int srow = tid >> 2, spart = tid & 3;   // 32 rows x 4 parts (16 halfs each)

    f32x4 acc0 = {0.f, 0.f, 0.f, 0.f}, acc1 = {0.f, 0.f, 0.f, 0.f};
    int4 pa0, pa1, pb0, pb1;
    constexpr int NK = DDIM / 64;  // 16

#define E_LOAD(ks)                                                                  \
    {                                                                               \
        const int k0_ = (ks) * 64 + spart * 16;                                     \
        pa0 = *(const int4*)&Ah[(size_t)(bm + srow) * DDIM + k0_];                  \
        pa1 = *(const int4*)&Ah[(size_t)(bm + srow) * DDIM + k0_ + 8];              \
        pb0 = *(const int4*)&WT[(size_t)(bn + srow) * DDIM + k0_];                  \
        pb1 = *(const int4*)&WT[(size_t)(bn + srow) * DDIM + k0_ + 8];              \
    }
#define E_STORE(buf)                                                                \
    {                                                                               \
        *(int4*)&As[buf][srow * 72 + spart * 16] = pa0;                             \
        *(int4*)&As[buf][srow * 72 + spart * 16 + 8] = pa1;                         \
        *(int4*)&Bs[buf][srow * 72 + spart * 16] = pb0;                             \
        *(int4*)&Bs[buf][srow * 72 + spart * 16 + 8] = pb1;                         \
    }

    E_LOAD(0);
    E_STORE(0);
    __syncthreads();
    int cur = 0;

    for (int ks = 0; ks < NK; ++ks) {
        if (ks + 1 < NK) E_LOAD(ks + 1);
#pragma unroll
        for (int kk = 0; kk < 2; ++kk) {
            half8 a = *(const half8*)&As[cur][(wrow + frow) * 72 + kk * 32 + fk * 8];
            half8 b0 = *(const half8*)&Bs[cur][frow * 72 + kk * 32 + fk * 8];
            half8 b1 = *(const half8*)&Bs[cur][(16 + frow) * 72 + kk * 32 + fk * 8];
            acc0 = __builtin_amdgcn_mfma_f32_16x16x32_f16(a, b0, acc0, 0, 0, 0);
            acc1 = __builtin_amdgcn_mfma_f32_16x16x32_f16(a, b1, acc1, 0, 0, 0);
        }
        if (ks + 1 < NK) E_STORE(cur ^ 1);
        __syncthreads();
        cur ^= 1;
    }
#undef E_LOAD
#undef E_STORE

    const int orow0 = bm + wrow + fk * 4;
    const int c0 = bn + frow, c1 = bn + 16 + frow;
    const float b0v = bias[c0], b1v = bias[c1];
#pragma unroll
    for (int r = 0; r < 4; ++r) {
        int row = orow0 + r;
        float v0 = acc0[r] + b0v;
        float v1 = acc1[r] + b1v;
        if (MODE == 1) {
            outH[(size_t)row * DDIM + c0] = (_Float16)fmaxf(v0, 0.f);
            outH[(size_t)row * DDIM + c1] = (_Float16)fmaxf(v1, 0.f);
        } else {
            outF[(size_t)row * DDIM + c0] = v0;
            outF[(size_t)row * DDIM + c1] = v1;
        }
    }
}

// ---------------- block reductions (256 threads = 4 waves) ----------------
__device__ inline float bred_sum(float x, float* sbuf) {
#pragma unroll
    for (int off = 32; off; off >>= 1) x += __shfl_down(x, off);
    __syncthreads();
    if ((threadIdx.x & 63) == 0) sbuf[threadIdx.x >> 6] = x;
    __syncthreads();
    return sbuf[0] + sbuf[1] + sbuf[2] + sbuf[3];
}
__device__ inline float bred_max(float x, float* sbuf) {
#pragma unroll
    for (int off = 32; off; off >>= 1) x = fmaxf(x, __shfl_down(x, off));
    __syncthreads();
    if ((threadIdx.x & 63) == 0) sbuf[threadIdx.x >> 6] = x;
    __syncthreads();
    return fmaxf(fmaxf(sbuf[0], sbuf[1]), fmaxf(sbuf[2], sbuf[3]));
}

// ---------------- rowops: softmax(S2), l2norm(Tr) -> fp16 uh,vh,rh,th,t2h; inv norms ----
// uh = 1024*u, vh = (32*A)^2 (fp16 underflow guard)
__global__ __launch_bounds__(256) void rowops(const float* __restrict__ S2,
                                              const float* __restrict__ Tr,
                                              const float* __restrict__ rr,
                                              const float* __restrict__ tt,
                                              _Float16* __restrict__ uh, _Float16* __restrict__ vh,
                                              _Float16* __restrict__ rh, _Float16* __restrict__ th,
                                              _Float16* __restrict__ t2h,
                                              float* __restrict__ inv_r,
                                              float* __restrict__ inv_t) {
    __shared__ float sbuf[4];
    const int b = blockIdx.x, tid = threadIdx.x;
    const size_t base = (size_t)b * DDIM + tid * 4;

    const float4 s4 = *(const float4*)&S2[base];
    float mx = fmaxf(fmaxf(s4.x, s4.y), fmaxf(s4.z, s4.w));
    mx = bred_max(mx, sbuf);
    float e0 = expf(s4.x - mx), e1 = expf(s4.y - mx), e2 = expf(s4.z - mx), e3 = expf(s4.w - mx);
    float sum = bred_sum(e0 + e1 + e2 + e3, sbuf);
    float invsum = 1.f / sum;

    const float4 tr4 = *(const float4*)&Tr[base];
    float ss = tr4.x * tr4.x + tr4.y * tr4.y + tr4.z * tr4.z + tr4.w * tr4.w;
    ss = bred_sum(ss, sbuf);
    float invn = 1.f / sqrtf(ss);

    float a0 = e0 * invsum, a1 = e1 * invsum, a2 = e2 * invsum, a3 = e3 * invsum;
    union { _Float16 h[4]; ushort4 u; } o;

    o.h[0] = (_Float16)(tr4.x * invn * a0 * 1024.f);
    o.h[1] = (_Float16)(tr4.y * invn * a1 * 1024.f);
    o.h[2] = (_Float16)(tr4.z * invn * a2 * 1024.f);
    o.h[3] = (_Float16)(tr4.w * invn * a3 * 1024.f);
    *(ushort4*)&uh[base] = o.u;

    float q0 = a0 * 32.f, q1 = a1 * 32.f, q2 = a2 * 32.f, q3 = a3 * 32.f;
    o.h[0] = (_Float16)(q0 * q0); o.h[1] = (_Float16)(q1 * q1);
    o.h[2] = (_Float16)(q2 * q2); o.h[3] = (_Float16)(q3 * q3);
    *(ushort4*)&vh[base] = o.u;

    const float4 r4 = *(const float4*)&rr[base];
    o.h[0] = (_Float16)r4.x; o.h[1] = (_Float16)r4.y;
    o.h[2] = (_Float16)r4.z; o.h[3] = (_Float16)r4.w;
    *(ushort4*)&rh[base] = o.u;

    const float4 t4 = *(const float4*)&tt[base];
    o.h[0] = (_Float16)t4.x; o.h[1] = (_Float16)t4.y;
    o.h[2] = (_Float16)t4.z; o.h[3] = (_Float16)t4.w;
    *(ushort4*)&th[base] = o.u;

    o.h[0] = (_Float16)(t4.x * t4.x); o.h[1] = (_Float16)(t4.y * t4.y);
    o.h[2] = (_Float16)(t4.z * t4.z); o.h[3] = (_Float16)(t4.w * t4.w);
    *(ushort4*)&t2h[base] = o.u;

    float sr = bred_sum(r4.x * r4.x + r4.y * r4.y + r4.z * r4.z + r4.w * r4.w, sbuf);
    float st = bred_sum(t4.x * t4.x + t4.y * t4.y + t4.z * t4.z + t4.w * t4.w, sbuf);
    if (tid == 0) {
        inv_r[b] = 1.f / sqrtf(sr);
        inv_t[b] = 1.f / sqrtf(st);
    }
}

// ---------------- score: fp16 MFMA, 3 dots, 32x32 tile, K-step 64, dbuf ----------------
__global__ __launch_bounds__(128) void score_mfma(const _Float16* __restrict__ uh,
                                                  const _Float16* __restrict__ vh,
                                                  const _Float16* __restrict__ rh,
                                                  const _Float16* __restrict__ th,
                                                  const _Float16* __restrict__ t2h,
                                                  const float* __restrict__ inv_r,
                                                  const float* __restrict__ inv_t,
                                                  float* __restrict__ out) {
    __shared__ __align__(16) _Float16 Us[2][32 * 72];
    __shared__ __align__(16) _Float16 Vs[2][32 * 72];
    __shared__ __align__(16) _Float16 Rs[2][32 * 72];
    __shared__ __align__(16) _Float16 Ts[2][32 * 72];
    __shared__ __align__(16) _Float16 Qs[2][32 * 72];

    const int tid = threadIdx.x;
    const int bm = blockIdx.x * 32, bn = blockIdx.y * 32;
    const int lane = tid & 63;
    const int wrow = (tid >> 6) * 16;
    const int frow = lane & 15, fk = lane >> 4;
    const int srow = tid >> 2, spart = tid & 3;

    f32x4 an0 = {0.f, 0.f, 0.f, 0.f}, an1 = an0;
    f32x4 ad0 = an0, ad1 = an0, ai0 = an0, ai1 = an0;
    int4 pu0, pu1, pv0, pv1, pr0, pr1, pt0, pt1, pq0, pq1;
    constexpr int NK = DDIM / 64;  // 16

#define S_LOAD(ks)                                                                   \
    {                                                                                \
        const size_t mo = (size_t)(bm + srow) * DDIM + (ks) * 64 + spart * 16;       \
        const size_t no = (size_t)(bn + srow) * DDIM + (ks) * 64 + spart * 16;       \
        pu0 = *(const int4*)&uh[mo];  pu1 = *(const int4*)&uh[mo + 8];               \
        pv0 = *(const int4*)&vh[mo];  pv1 = *(const int4*)&vh[mo + 8];               \
        pr0 = *(const int4*)&rh[mo];  pr1 = *(const int4*)&rh[mo + 8];               \
        pt0 = *(const int4*)&th[no];  pt1 = *(const int4*)&th[no + 8];               \
        pq0 = *(const int4*)&t2h[no]; pq1 = *(const int4*)&t2h[no + 8];              \
    }
#define S_STORE(buf)                                                                 \
    {                                                                                \
        const int lo = srow * 72 + spart * 16;                                       \
        *(int4*)&Us[buf][lo] = pu0; *(int4*)&Us[buf][lo + 8] = pu1;                  \
        *(int4*)&Vs[buf][lo] = pv0; *(int4*)&Vs[buf][lo + 8] = pv1;                  \
        *(int4*)&Rs[buf][lo] = pr0; *(int4*)&Rs[buf][lo + 8] = pr1;                  \
        *(int4*)&Ts[buf][lo] = pt0; *(int4*)&Ts[buf][lo + 8] = pt1;                  \
        *(int4*)&Qs[buf][lo] = pq0; *(int4*)&Qs[buf][lo + 8] = pq1;                  \
    }

    S_LOAD(0);
    S_STORE(0);
    __syncthreads();
    int cur = 0;

    for (int ks = 0; ks < NK; ++ks) {
        if (ks + 1 < NK) S_LOAD(ks + 1);
#pragma unroll
        for (int kk = 0; kk < 2; ++kk) {
            const int ao = (wrow + frow) * 72 + kk * 32 + fk * 8;
            const int bo0 = frow * 72 + kk * 32 + fk * 8;
            const int bo1 = (16 + frow) * 72 + kk * 32 + fk * 8;
            half8 au = *(const half8*)&Us[cur][ao];
            half8 av = *(const half8*)&Vs[cur][ao];
            half8 ar = *(const half8*)&Rs[cur][ao];
            half8 bt0 = *(const half8*)&Ts[cur][bo0];
            half8 bt1 = *(const half8*)&Ts[cur][bo1];
            half8 bq0 = *(const half8*)&Qs[cur][bo0];
            half8 bq1 = *(const half8*)&Qs[cur][bo1];
            an0 = __builtin_amdgcn_mfma_f32_16x16x32_f16(au, bt0, an0, 0, 0, 0);
            an1 = __builtin_amdgcn_mfma_f32_16x16x32_f16(au, bt1, an1, 0, 0, 0);
            ad0 = __builtin_amdgcn_mfma_f32_16x16x32_f16(av, bq0, ad0, 0, 0, 0);
            ad1 = __builtin_amdgcn_mfma_f32_16x16x32_f16(av, bq1, ad1, 0, 0, 0);
            ai0 = __builtin_amdgcn_mfma_f32_16x16x32_f16(ar, bt0, ai0, 0, 0, 0);
            ai1 = __builtin_amdgcn_mfma_f32_16x16x32_f16(ar, bt1, ai1, 0, 0, 0);
        }
        if (ks + 1 < NK) S_STORE(cur ^ 1);
        __syncthreads();
        cur ^= 1;
    }
#undef S_LOAD
#undef S_STORE

    const int orow0 = bm + wrow + fk * 4;
    const int c0 = bn + frow, c1 = bn + 16 + frow;
    const float it0 = inv_t[c0], it1 = inv_t[c1];
#pragma unroll
    for (int r = 0; r < 4; ++r) {
        int row = orow0 + r;
        float ir = inv_r[row];
        float em0 = an0[r] / (32.f * sqrtf(ad0[r]));
        float em1 = an1[r] / (32.f * sqrtf(ad1[r]));
        out[(size_t)row * BDIM + c0] = em0 + ai0[r] * ir * it0;
        out[(size_t)row * BDIM + c1] = em1 + ai1[r] * ir * it1;
    }
}

extern "C" void kernel_launch(void* const* d_in, const int* in_sizes, int n_in, void* d_out,
                              int out_size, void* d_ws, size_t ws_size, hipStream_t stream) {
    const float* r = (const float*)d_in[0];
    const float* m = (const float*)d_in[1];
    const float* t = (const float*)d_in[2];
    const int* ntid = (const int*)d_in[3];
    const int* nlen = (const int*)d_in[4];
    const int* ant = (const int*)d_in[5];
    const float* embed = (const float*)d_in[6];
    const float* noun_W = (const float*)d_in[7];
    const float* noun_b = (const float*)d_in[8];
    const float* em_W1 = (const float*)d_in[9];
    const float* em_b1 = (const float*)d_in[10];
    const float* em_W2 = (const float*)d_in[11];
    const float* em_b2 = (const float*)d_in[12];
    const float* tr_W = (const float*)d_in[13];
    const float* tr_b = (const float*)d_in[14];
    const int* t2i = (const int*)d_in[15];

    float* score = (float*)d_out;
    float* concepts = score + (size_t)SELEM;

    // ---- flat workspace layout (~19.4 MB; observed ws_size ~268 MB across rounds) ----
    char* base = (char*)d_ws;
    size_t off = 0;
    auto alloc = [&](size_t bytes) { char* p = base + off; off += (bytes + 255) & ~(size_t)255; return p; };
    int* rowtok = (int*)alloc(NROWS * 4);
    float* inv_r = (float*)alloc(BDIM * 4);
    float* inv_t = (float*)alloc(BDIM * 4);
    ushort* Abf = (ushort*)alloc((size_t)NROWS * CK * 2);
    ushort* BbfT = (ushort*)alloc((size_t)DDIM * CK * 2);
    _Float16* WT1 = (_Float16*)alloc((size_t)DDIM * DDIM * 2);
    _Float16* WT2 = (_Float16*)alloc((size_t)DDIM * DDIM * 2);
    _Float16* WT3 = (_Float16*)alloc((size_t)DDIM * DDIM * 2);
    _Float16* mh = (_Float16*)alloc((size_t)FELEM * 2);
    _Float16* hh = (_Float16*)alloc((size_t)FELEM * 2);
    float* S2 = (float*)alloc((size_t)FELEM * 4);
    float* Tr = (float*)alloc((size_t)FELEM * 4);
    _Float16* uh = (_Float16*)alloc((size_t)FELEM * 2);
    _Float16* vh = (_Float16*)alloc((size_t)FELEM * 2);
    _Float16* rh = (_Float16*)alloc((size_t)FELEM * 2);
    _Float16* th = (_Float16*)alloc((size_t)FELEM * 2);
    _Float16* t2h = (_Float16*)alloc((size_t)FELEM * 2);

    prepA<<<(NROWS * (CK / 4) + 255) / 256, 256, 0, stream>>>(embed, ntid, nlen, ant, t2i,
                                                             Abf, rowtok);
    prepB<<<dim3(CK / 32, DDIM / 32), 256, 0, stream>>>(noun_W, BbfT);

    dim3 gC(NROWS / 128, DDIM / 128);  // 48 x 8
    concepts_mfma<<<gC, 256, 0, stream>>>(Abf, BbfT, rowtok, noun_b, concepts);

    prep_em<<<dim3(32, 32, 4), 256, 0, stream>>>(em_W1, em_W2, tr_W, WT1, WT2, WT3, m, mh);

    dim3 gG(BDIM / 32, DDIM / 32);     // 12 x 32 = 384 blocks
    emgemm<1><<<gG, 128, 0, stream>>>(mh, WT1, em_b1, nullptr, hh);
    emgemm<0><<<gG, 128, 0, stream>>>(hh, WT2, em_b2, S2, nullptr);
    emgemm<0><<<gG, 128, 0, stream>>>(mh, WT3, tr_b, Tr, nullptr);

    rowops<<<BDIM, 256, 0, stream>>>(S2, Tr, r, t, uh, vh, rh, th, t2h, inv_r, inv_t);

    dim3 gS(BDIM / 32, BDIM / 32);     // 12 x 12
    score_mfma<<<gS, 128, 0, stream>>>(uh, vh, rh, th, t2h, inv_r, inv_t, score);
}

// Round 6
// 59.386 us; speedup vs baseline: 5.9797x; 1.2180x over previous
//
#include <hip/hip_runtime.h>
#include <hip/hip_bf16.h>

#define BDIM 384
#define DDIM 1024
#define LDIM 16
#define WD 300
#define CK 320                 // concepts K padded to 32-multiple for MFMA
#define NROWS (BDIM * LDIM)    // 6144
#define FELEM (BDIM * DDIM)    // 393216
#define SELEM (BDIM * BDIM)    // 147456

typedef __attribute__((ext_vector_type(8))) short short8v;     // 8 bf16
typedef _Float16 half8 __attribute__((ext_vector_type(8)));    // 8 fp16
typedef __attribute__((ext_vector_type(4))) float f32x4;

__device__ inline ushort f2bf(float x) {
    union { float f; unsigned u; } c; c.f = x;
    unsigned u = c.u;
    unsigned r = (u + 0x7fffu + ((u >> 16) & 1u)) >> 16;   // RNE
    return (ushort)r;
}

// ---------------- prep_all: fused prepA-gather | prepB | 3x transW | cvt_m ----------------
// 1D grid role decode: [0,1920) prepA, [1920,2240) prepB, [2240,5312) transW z=bb>>10,
// [5312,5696) cvt_m.
#define PRE_A 1920
#define PRE_B (PRE_A + 320)
#define PRE_T (PRE_B + 3072)
#define PRE_M (PRE_T + 384)
__global__ __launch_bounds__(256) void prep_all(
    const float* __restrict__ embed, const int* __restrict__ ntid,
    const int* __restrict__ nlen, const int* __restrict__ ant, const int* __restrict__ t2i,
    ushort* __restrict__ Abf, int* __restrict__ rowtok,
    const float* __restrict__ nW, ushort* __restrict__ BbfT,
    const float* __restrict__ W1, const float* __restrict__ W2, const float* __restrict__ W3,
    _Float16* __restrict__ WT1, _Float16* __restrict__ WT2, _Float16* __restrict__ WT3,
    const float* __restrict__ m, _Float16* __restrict__ mh) {
    __shared__ float tile[32][33];
    const int b = blockIdx.x, t = threadIdx.x;

    if (b < PRE_A) {   // --- prepA: gather embed rows -> bf16 [NROWS][CK] + rowtok ---
        int idx = b * 256 + t;
        int row = idx / (CK / 4);
        int q = idx - row * (CK / 4);
        int tok = ntid[row];
        int w = t2i[tok];
        int eff = (w > 0) ? ant[w] : tok;            // `if weight_idx:` falsy-0 semantics
        bool valid = (row & 15) < nlen[row >> 4];
        if (q == 0) rowtok[row] = valid ? eff : -1;
        ushort4 o = {0, 0, 0, 0};
        if (valid && q < WD / 4) {
            float4 v = *(const float4*)&embed[(size_t)eff * WD + q * 4];
            o.x = f2bf(v.x); o.y = f2bf(v.y); o.z = f2bf(v.z); o.w = f2bf(v.w);
        }
        *(ushort4*)&Abf[(size_t)row * CK + q * 4] = o;
        return;
    }
    if (b < PRE_B) {   // --- prepB: transpose noun_W [300][1024] -> bf16 [1024][CK] ---
        int bb = b - PRE_A;
        const int k0 = (bb % 10) * 32, c0 = (bb / 10) * 32;
        const int r = t >> 3, q = t & 7;
        int k = k0 + r;
        float4 v = {0, 0, 0, 0};
        if (k < WD) v = *(const float4*)&nW[(size_t)k * DDIM + c0 + q * 4];
        tile[r][q * 4 + 0] = v.x; tile[r][q * 4 + 1] = v.y;
        tile[r][q * 4 + 2] = v.z; tile[r][q * 4 + 3] = v.w;
        __syncthreads();
        ushort4 o;
        o.x = f2bf(tile[q * 4 + 0][r]);
        o.y = f2bf(tile[q * 4 + 1][r]);
        o.z = f2bf(tile[q * 4 + 2][r]);
        o.w = f2bf(tile[q * 4 + 3][r]);
        *(ushort4*)&BbfT[(size_t)(c0 + r) * CK + k0 + q * 4] = o;
        return;
    }
    if (b < PRE_T) {   // --- transW: W [1024][1024] f32 -> WT [n][k] fp16 ---
        int bb = b - PRE_B;
        int z = bb >> 10, rem = bb & 1023;
        const float* W = (z == 0) ? W1 : (z == 1) ? W2 : W3;
        _Float16* WT = (z == 0) ? WT1 : (z == 1) ? WT2 : WT3;
        const int k0 = (rem & 31) * 32, c0 = (rem >> 5) * 32;
        const int r = t >> 3, q = t & 7;
        float4 v = *(const float4*)&W[(size_t)(k0 + r) * DDIM + c0 + q * 4];
        tile[r][q * 4 + 0] = v.x; tile[r][q * 4 + 1] = v.y;
        tile[r][q * 4 + 2] = v.z; tile[r][q * 4 + 3] = v.w;
        __syncthreads();
        union { _Float16 h[4]; ushort4 u; } o;
        o.h[0] = (_Float16)tile[q * 4 + 0][r];
        o.h[1] = (_Float16)tile[q * 4 + 1][r];
        o.h[2] = (_Float16)tile[q * 4 + 2][r];
        o.h[3] = (_Float16)tile[q * 4 + 3][r];
        *(ushort4*)&WT[(size_t)(c0 + r) * DDIM + k0 + q * 4] = o.u;
        return;
    }
    {                  // --- cvt_m: m -> fp16 ---
        int bb = b - PRE_T;
        int i = bb * 1024 + t * 4;
        float4 v = *(const float4*)&m[i];
        union { _Float16 h[4]; ushort4 u; } o;
        o.h[0] = (_Float16)v.x; o.h[1] = (_Float16)v.y;
        o.h[2] = (_Float16)v.z; o.h[3] = (_Float16)v.w;
        *(ushort4*)&mh[i] = o.u;
    }
}

// ---------------- concepts: 128x128 MFMA bf16 GEMM, K=CK, dbuf, staged C-write ----------
__global__ __launch_bounds__(256) void concepts_mfma(const ushort* __restrict__ Abf,
                                                     const ushort* __restrict__ BbfT,
                                                     const int* __restrict__ rowtok,
                                                     const float* __restrict__ bias,
                                                     float* __restrict__ C) {
    union SMem {
        struct { ushort As[2][128 * 40]; ushort Bs[2][128 * 40]; } g;
        float cst[2][128 * 68];   // stride 68: 16B-aligned rows, fk bank-shift {0,16} -> 2-way(free)
    };
    __shared__ __align__(16) SMem sm;
    __shared__ int stok[128];

    const int tid = threadIdx.x;
    const int bm = blockIdx.x * 128, bn = blockIdx.y * 128;
    if (tid < 128) stok[tid] = rowtok[bm + tid];

    const int w = tid >> 6, lane = tid & 63;
    const int wrow = (w & 1) * 64, wcol = (w >> 1) * 64;
    const int frow = lane & 15, fk = lane >> 4;
    const int srow = tid >> 2, spart = tid & 3;

    f32x4 acc[4][4];
#pragma unroll
    for (int i = 0; i < 4; ++i)
#pragma unroll
        for (int j = 0; j < 4; ++j) acc[i][j] = (f32x4){0.f, 0.f, 0.f, 0.f};

    int4 pa0, pa1, pb0, pb1;
    constexpr int NK = CK / 32;  // 10

#define C_LOAD(ks)                                                                   \
    {                                                                                \
        const int k0_ = (ks) * 32;                                                   \
        pa0 = *(const int4*)&Abf[(size_t)(bm + srow) * CK + k0_ + spart * 8];        \
        pa1 = *(const int4*)&Abf[(size_t)(bm + 64 + srow) * CK + k0_ + spart * 8];   \
        pb0 = *(const int4*)&BbfT[(size_t)(bn + srow) * CK + k0_ + spart * 8];       \
        pb1 = *(const int4*)&BbfT[(size_t)(bn + 64 + srow) * CK + k0_ + spart * 8];  \
    }
#define C_STORE(buf)                                                                 \
    {                                                                                \
        *(int4*)&sm.g.As[buf][srow * 40 + spart * 8] = pa0;                          \
        *(int4*)&sm.g.As[buf][(64 + srow) * 40 + spart * 8] = pa1;                   \
        *(int4*)&sm.g.Bs[buf][srow * 40 + spart * 8] = pb0;                          \
        *(int4*)&sm.g.Bs[buf][(64 + srow) * 40 + spart * 8] = pb1;                   \
    }

    C_LOAD(0);
    C_STORE(0);
    __syncthreads();
    int cur = 0;

    for (int ks = 0; ks < NK; ++ks) {
        if (ks + 1 < NK) C_LOAD(ks + 1);
        short8v a[4], b[4];
#pragma unroll
        for (int i = 0; i < 4; ++i)
            a[i] = *(const short8v*)&sm.g.As[cur][(wrow + i * 16 + frow) * 40 + fk * 8];
#pragma unroll
        for (int j = 0; j < 4; ++j)
            b[j] = *(const short8v*)&sm.g.Bs[cur][(wcol + j * 16 + frow) * 40 + fk * 8];
#pragma unroll
        for (int i = 0; i < 4; ++i)
#pragma unroll
            for (int j = 0; j < 4; ++j)
                acc[i][j] = __builtin_amdgcn_mfma_f32_16x16x32_bf16(a[i], b[j], acc[i][j], 0, 0, 0);
        if (ks + 1 < NK) C_STORE(cur ^ 1);
        __syncthreads();
        cur ^= 1;
    }
#undef C_LOAD
#undef C_STORE

    // ---- staged epilogue: acc -> LDS (f32, stride 68) -> float4 global stores ----
    const int half = w >> 1;   // waves 0,1: cols 0-63; waves 2,3: cols 64-127
#pragma unroll
    for (int i = 0; i < 4; ++i)
#pragma unroll
        for (int j = 0; j < 4; ++j)
#pragma unroll
            for (int r2 = 0; r2 < 4; ++r2) {
                int row = wrow + i * 16 + fk * 4 + r2;
                int col = j * 16 + frow;
                sm.cst[half][row * 68 + col] = acc[i][j][r2];
            }
    __syncthreads();

#pragma unroll
    for (int it = 0; it < 16; ++it) {
        int f = it * 256 + tid;          // 4096 float4 total
        int seg = f & 15;                // float4 within row-half
        int rowh = f >> 4;
        int h2 = rowh >> 7, row = rowh & 127;
        float4 o = *(const float4*)&sm.cst[h2][row * 68 + seg * 4];
        int colb = h2 * 64 + seg * 4;
        float4 bv = *(const float4*)&bias[bn + colb];
        bool zero = (stok[row] < 0);
        o.x = zero ? 0.f : o.x + bv.x;
        o.y = zero ? 0.f : o.y + bv.y;
        o.z = zero ? 0.f : o.z + bv.z;
        o.w = zero ? 0.f : o.w + bv.w;
        *(float4*)&C[(size_t)(bm + row) * DDIM + bn + colb] = o;
    }
}

// ---------------- em GEMM: fp16 MFMA, 32x32 tile, 128 thr, K-step 64, dbuf ----------------
// MODE 0: out = acc + bias (fp32); MODE 1: out = fp16(relu(acc + bias)); MODE 2: runtime z
template <int MODE>
__device__ __forceinline__ void emgemm_body(const _Float16* __restrict__ Ah,
                                            const _Float16* __restrict__ WT,
                                            const float* __restrict__ bias,
                                            float* __restrict__ outF,
                                            _Float16* __restrict__ outH) {
    __shared__ __align__(16) _Float16 As[2][32 * 72];
    __shared__ __align__(16) _Float16 Bs[2][32 * 72];
    const int tid = threadIdx.x;
    const int bm = blockIdx.x * 32, bn = blockIdx.y * 32;
    const int lane = tid & 63;
    const int wrow = (tid >> 6) * 16;
    const int frow = lane & 15, fk = lane >> 4;
    const int srow = tid >> 2, spart = tid & 3;

    f32x4 acc0 = {0.f, 0.f, 0.f, 0.f}, acc1 = {0.f, 0.f, 0.f, 0.f};
    int4 pa0, pa1, pb0, pb1;
    constexpr int NK = DDIM / 64;  // 16

#define E_LOAD(ks)                                                                  \
    {                                                                               \
        const int k0_ = (ks) * 64 + spart * 16;                                     \
        pa0 = *(const int4*)&Ah[(size_t)(bm + srow) * DDIM + k0_];                  \
        pa1 = *(const int4*)&Ah[(size_t)(bm + srow) * DDIM + k0_ + 8];              \
        pb0 = *(const int4*)&WT[(size_t)(bn + srow) * DDIM + k0_];                  \
        pb1 = *(const int4*)&WT[(size_t)(bn + srow) * DDIM + k0_ + 8];              \
    }
#define E_STORE(buf)                                                                \
    {                                                                               \
        *(int4*)&As[buf][srow * 72 + spart * 16] = pa0;                             \
        *(int4*)&As[buf][srow * 72 + spart * 16 + 8] = pa1;                         \
        *(int4*)&Bs[buf][srow * 72 + spart * 16] = pb0;                             \
        *(int4*)&Bs[buf][srow * 72 + spart * 16 + 8] = pb1;                         \
    }

    E_LOAD(0);
    E_STORE(0);
    __syncthreads();
    int cur = 0;

    for (int ks = 0; ks < NK; ++ks) {
        if (ks + 1 < NK) E_LOAD(ks + 1);
#pragma unroll
        for (int kk = 0; kk < 2; ++kk) {
            half8 a = *(const half8*)&As[cur][(wrow + frow) * 72 + kk * 32 + fk * 8];
            half8 b0 = *(const half8*)&Bs[cur][frow * 72 + kk * 32 + fk * 8];
            half8 b1 = *(const half8*)&Bs[cur][(16 + frow) * 72 + kk * 32 + fk * 8];
            acc0 = __builtin_amdgcn_mfma_f32_16x16x32_f16(a, b0, acc0, 0, 0, 0);
            acc1 = __builtin_amdgcn_mfma_f32_16x16x32_f16(a, b1, acc1, 0, 0, 0);
        }
        if (ks + 1 < NK) E_STORE(cur ^ 1);
        __syncthreads();
        cur ^= 1;
    }
#undef E_LOAD
#undef E_STORE

    const int orow0 = bm + wrow + fk * 4;
    const int c0 = bn + frow, c1 = bn + 16 + frow;
    const float b0v = bias[c0], b1v = bias[c1];
#pragma unroll
    for (int r = 0; r < 4; ++r) {
        int row = orow0 + r;
        float v0 = acc0[r] + b0v;
        float v1 = acc1[r] + b1v;
        if (MODE == 1) {
            outH[(size_t)row * DDIM + c0] = (_Float16)fmaxf(v0, 0.f);
            outH[(size_t)row * DDIM + c1] = (_Float16)fmaxf(v1, 0.f);
        } else {
            outF[(size_t)row * DDIM + c0] = v0;
            outF[(size_t)row * DDIM + c1] = v1;
        }
    }
}

// z=0: hh = fp16(relu(mh@WT1+b1)); z=1: Tr = mh@WT3+b3 (f32)
__global__ __launch_bounds__(128) void emgemm13(const _Float16* __restrict__ mh,
                                                const _Float16* __restrict__ WT1,
                                                const _Float16* __restrict__ WT3,
                                                const float* __restrict__ b1,
                                                const float* __restrict__ b3,
                                                _Float16* __restrict__ hh,
                                                float* __restrict__ Tr) {
    if (blockIdx.z == 0)
        emgemm_body<1>(mh, WT1, b1, nullptr, hh);
    else
        emgemm_body<0>(mh, WT3, b3, Tr, nullptr);
}

__global__ __launch_bounds__(128) void emgemm2(const _Float16* __restrict__ hh,
                                               const _Float16* __restrict__ WT2,
                                               const float* __restrict__ b2,
                                               float* __restrict__ S2) {
    emgemm_body<0>(hh, WT2, b2, S2, nullptr);
}

// ---------------- block reductions (256 threads = 4 waves) ----------------
__device__ inline float bred_sum(float x, float* sbuf) {
#pragma unroll
    for (int off = 32; off; off >>= 1) x += __shfl_down(x, off);
    __syncthreads();
    if ((threadIdx.x & 63) == 0) sbuf[threadIdx.x >> 6] = x;
    __syncthreads();
    return sbuf[0] + sbuf[1] + sbuf[2] + sbuf[3];
}
__device__ inline float bred_max(float x, float* sbuf) {
#pragma unroll
    for (int off = 32; off; off >>= 1) x = fmaxf(x, __shfl_down(x, off));
    __syncthreads();
    if ((threadIdx.x & 63) == 0) sbuf[threadIdx.x >> 6] = x;
    __syncthreads();
    return fmaxf(fmaxf(sbuf[0], sbuf[1]), fmaxf(sbuf[2], sbuf[3]));
}

// ---------------- rowops: softmax(S2), l2norm(Tr) -> fp16 uh,vh,rh,th,t2h; inv norms ----
// uh = 1024*u, vh = (32*A)^2 (fp16 underflow guard)
__global__ __launch_bounds__(256) void rowops(const float* __restrict__ S2,
                                              const float* __restrict__ Tr,
                                              const float* __restrict__ rr,
                                              const float* __restrict__ tt,
                                              _Float16* __restrict__ uh, _Float16* __restrict__ vh,
                                              _Float16* __restrict__ rh, _Float16* __restrict__ th,
                                              _Float16* __restrict__ t2h,
                                              float* __restrict__ inv_r,
                                              float* __restrict__ inv_t) {
    __shared__ float sbuf[4];
    const int b = blockIdx.x, tid = threadIdx.x;
    const size_t base = (size_t)b * DDIM + tid * 4;

    const float4 s4 = *(const float4*)&S2[base];
    float mx = fmaxf(fmaxf(s4.x, s4.y), fmaxf(s4.z, s4.w));
    mx = bred_max(mx, sbuf);
    float e0 = expf(s4.x - mx), e1 = expf(s4.y - mx), e2 = expf(s4.z - mx), e3 = expf(s4.w - mx);
    float sum = bred_sum(e0 + e1 + e2 + e3, sbuf);
    float invsum = 1.f / sum;

    const float4 tr4 = *(const float4*)&Tr[base];
    float ss = tr4.x * tr4.x + tr4.y * tr4.y + tr4.z * tr4.z + tr4.w * tr4.w;
    ss = bred_sum(ss, sbuf);
    float invn = 1.f / sqrtf(ss);

    float a0 = e0 * invsum, a1 = e1 * invsum, a2 = e2 * invsum, a3 = e3 * invsum;
    union { _Float16 h[4]; ushort4 u; } o;

    o.h[0] = (_Float16)(tr4.x * invn * a0 * 1024.f);
    o.h[1] = (_Float16)(tr4.y * invn * a1 * 1024.f);
    o.h[2] = (_Float16)(tr4.z * invn * a2 * 1024.f);
    o.h[3] = (_Float16)(tr4.w * invn * a3 * 1024.f);
    *(ushort4*)&uh[base] = o.u;

    float q0 = a0 * 32.f, q1 = a1 * 32.f, q2 = a2 * 32.f, q3 = a3 * 32.f;
    o.h[0] = (_Float16)(q0 * q0); o.h[1] = (_Float16)(q1 * q1);
    o.h[2] = (_Float16)(q2 * q2); o.h[3] = (_Float16)(q3 * q3);
    *(ushort4*)&vh[base] = o.u;

    const float4 r4 = *(const float4*)&rr[base];
    o.h[0] = (_Float16)r4.x; o.h[1] = (_Float16)r4.y;
    o.h[2] = (_Float16)r4.z; o.h[3] = (_Float16)r4.w;
    *(ushort4*)&rh[base] = o.u;

    const float4 t4 = *(const float4*)&tt[base];
    o.h[0] = (_Float16)t4.x; o.h[1] = (_Float16)t4.y;
    o.h[2] = (_Float16)t4.z; o.h[3] = (_Float16)t4.w;
    *(ushort4*)&th[base] = o.u;

    o.h[0] = (_Float16)(t4.x * t4.x); o.h[1] = (_Float16)(t4.y * t4.y);
    o.h[2] = (_Float16)(t4.z * t4.z); o.h[3] = (_Float16)(t4.w * t4.w);
    *(ushort4*)&t2h[base] = o.u;

    float sr = bred_sum(r4.x * r4.x + r4.y * r4.y + r4.z * r4.z + r4.w * r4.w, sbuf);
    float st = bred_sum(t4.x * t4.x + t4.y * t4.y + t4.z * t4.z + t4.w * t4.w, sbuf);
    if (tid == 0) {
        inv_r[b] = 1.f / sqrtf(sr);
        inv_t[b] = 1.f / sqrtf(st);
    }
}

// ---------------- score: fp16 MFMA, 3 dots, 32x32 tile, K-step 64, dbuf ----------------
__global__ __launch_bounds__(128) void score_mfma(const _Float16* __restrict__ uh,
                                                  const _Float16* __restrict__ vh,
                                                  const _Float16* __restrict__ rh,
                                                  const _Float16* __restrict__ th,
                                                  const _Float16* __restrict__ t2h,
                                                  const float* __restrict__ inv_r,
                                                  const float* __restrict__ inv_t,
                                                  float* __restrict__ out) {
    __shared__ __align__(16) _Float16 Us[2][32 * 72];
    __shared__ __align__(16) _Float16 Vs[2][32 * 72];
    __shared__ __align__(16) _Float16 Rs[2][32 * 72];
    __shared__ __align__(16) _Float16 Ts[2][32 * 72];
    __shared__ __align__(16) _Float16 Qs[2][32 * 72];

    const int tid = threadIdx.x;
    const int bm = blockIdx.x * 32, bn = blockIdx.y * 32;
    const int lane = tid & 63;
    const int wrow = (tid >> 6) * 16;
    const int frow = lane & 15, fk = lane >> 4;
    const int srow = tid >> 2, spart = tid & 3;

    f32x4 an0 = {0.f, 0.f, 0.f, 0.f}, an1 = an0;
    f32x4 ad0 = an0, ad1 = an0, ai0 = an0, ai1 = an0;
    int4 pu0, pu1, pv0, pv1, pr0, pr1, pt0, pt1, pq0, pq1;
    constexpr int NK = DDIM / 64;  // 16

#define S_LOAD(ks)                                                                   \
    {                                                                                \
        const size_t mo = (size_t)(bm + srow) * DDIM + (ks) * 64 + spart * 16;       \
        const size_t no = (size_t)(bn + srow) * DDIM + (ks) * 64 + spart * 16;       \
        pu0 = *(const int4*)&uh[mo];  pu1 = *(const int4*)&uh[mo + 8];               \
        pv0 = *(const int4*)&vh[mo];  pv1 = *(const int4*)&vh[mo + 8];               \
        pr0 = *(const int4*)&rh[mo];  pr1 = *(const int4*)&rh[mo + 8];               \
        pt0 = *(const int4*)&th[no];  pt1 = *(const int4*)&th[no + 8];               \
        pq0 = *(const int4*)&t2h[no]; pq1 = *(const int4*)&t2h[no + 8];              \
    }
#define S_STORE(buf)                                                                 \
    {                                                                                \
        const int lo = srow * 72 + spart * 16;                                       \
        *(int4*)&Us[buf][lo] = pu0; *(int4*)&Us[buf][lo + 8] = pu1;                  \
        *(int4*)&Vs[buf][lo] = pv0; *(int4*)&Vs[buf][lo + 8] = pv1;                  \
        *(int4*)&Rs[buf][lo] = pr0; *(int4*)&Rs[buf][lo + 8] = pr1;                  \
        *(int4*)&Ts[buf][lo] = pt0; *(int4*)&Ts[buf][lo + 8] = pt1;                  \
        *(int4*)&Qs[buf][lo] = pq0; *(int4*)&Qs[buf][lo + 8] = pq1;                  \
    }

    S_LOAD(0);
    S_STORE(0);
    __syncthreads();
    int cur = 0;

    for (int ks = 0; ks < NK; ++ks) {
        if (ks + 1 < NK) S_LOAD(ks + 1);
#pragma unroll
        for (int kk = 0; kk < 2; ++kk) {
            const int ao = (wrow + frow) * 72 + kk * 32 + fk * 8;
            const int bo0 = frow * 72 + kk * 32 + fk * 8;
            const int bo1 = (16 + frow) * 72 + kk * 32 + fk * 8;
            half8 au = *(const half8*)&Us[cur][ao];
            half8 av = *(const half8*)&Vs[cur][ao];
            half8 ar = *(const half8*)&Rs[cur][ao];
            half8 bt0 = *(const half8*)&Ts[cur][bo0];
            half8 bt1 = *(const half8*)&Ts[cur][bo1];
            half8 bq0 = *(const half8*)&Qs[cur][bo0];
            half8 bq1 = *(const half8*)&Qs[cur][bo1];
            an0 = __builtin_amdgcn_mfma_f32_16x16x32_f16(au, bt0, an0, 0, 0, 0);
            an1 = __builtin_amdgcn_mfma_f32_16x16x32_f16(au, bt1, an1, 0, 0, 0);
            ad0 = __builtin_amdgcn_mfma_f32_16x16x32_f16(av, bq0, ad0, 0, 0, 0);
            ad1 = __builtin_amdgcn_mfma_f32_16x16x32_f16(av, bq1, ad1, 0, 0, 0);
            ai0 = __builtin_amdgcn_mfma_f32_16x16x32_f16(ar, bt0, ai0, 0, 0, 0);
            ai1 = __builtin_amdgcn_mfma_f32_16x16x32_f16(ar, bt1, ai1, 0, 0, 0);
        }
        if (ks + 1 < NK) S_STORE(cur ^ 1);
        __syncthreads();
        cur ^= 1;
    }
#undef S_LOAD
#undef S_STORE

    const int orow0 = bm + wrow + fk * 4;
    const int c0 = bn + frow, c1 = bn + 16 + frow;
    const float it0 = inv_t[c0], it1 = inv_t[c1];
#pragma unroll
    for (int r = 0; r < 4; ++r) {
        int row = orow0 + r;
        float ir = inv_r[row];
        float em0 = an0[r] / (32.f * sqrtf(ad0[r]));
        float em1 = an1[r] / (32.f * sqrtf(ad1[r]));
        out[(size_t)row * BDIM + c0] = em0 + ai0[r] * ir * it0;
        out[(size_t)row * BDIM + c1] = em1 + ai1[r] * ir * it1;
    }
}

extern "C" void kernel_launch(void* const* d_in, const int* in_sizes, int n_in, void* d_out,
                              int out_size, void* d_ws, size_t ws_size, hipStream_t stream) {
    const float* r = (const float*)d_in[0];
    const float* m = (const float*)d_in[1];
    const float* t = (const float*)d_in[2];
    const int* ntid = (const int*)d_in[3];
    const int* nlen = (const int*)d_in[4];
    const int* ant = (const int*)d_in[5];
    const float* embed = (const float*)d_in[6];
    const float* noun_W = (const float*)d_in[7];
    const float* noun_b = (const float*)d_in[8];
    const float* em_W1 = (const float*)d_in[9];
    const float* em_b1 = (const float*)d_in[10];
    const float* em_W2 = (const float*)d_in[11];
    const float* em_b2 = (const float*)d_in[12];
    const float* tr_W = (const float*)d_in[13];
    const float* tr_b = (const float*)d_in[14];
    const int* t2i = (const int*)d_in[15];

    float* score = (float*)d_out;
    float* concepts = score + (size_t)SELEM;

    // ---- flat workspace layout (~19.4 MB; observed ws_size ~268 MB) ----
    char* base = (char*)d_ws;
    size_t off = 0;
    auto alloc = [&](size_t bytes) { char* p = base + off; off += (bytes + 255) & ~(size_t)255; return p; };
    int* rowtok = (int*)alloc(NROWS * 4);
    float* inv_r = (float*)alloc(BDIM * 4);
    float* inv_t = (float*)alloc(BDIM * 4);
    ushort* Abf = (ushort*)alloc((size_t)NROWS * CK * 2);
    ushort* BbfT = (ushort*)alloc((size_t)DDIM * CK * 2);
    _Float16* WT1 = (_Float16*)alloc((size_t)DDIM * DDIM * 2);
    _Float16* WT2 = (_Float16*)alloc((size_t)DDIM * DDIM * 2);
    _Float16* WT3 = (_Float16*)alloc((size_t)DDIM * DDIM * 2);
    _Float16* mh = (_Float16*)alloc((size_t)FELEM * 2);
    _Float16* hh = (_Float16*)alloc((size_t)FELEM * 2);
    float* S2 = (float*)alloc((size_t)FELEM * 4);
    float* Tr = (float*)alloc((size_t)FELEM * 4);
    _Float16* uh = (_Float16*)alloc((size_t)FELEM * 2);
    _Float16* vh = (_Float16*)alloc((size_t)FELEM * 2);
    _Float16* rh = (_Float16*)alloc((size_t)FELEM * 2);
    _Float16* th = (_Float16*)alloc((size_t)FELEM * 2);
    _Float16* t2h = (_Float16*)alloc((size_t)FELEM * 2);

    prep_all<<<PRE_M, 256, 0, stream>>>(embed, ntid, nlen, ant, t2i, Abf, rowtok,
                                        noun_W, BbfT, em_W1, em_W2, tr_W, WT1, WT2, WT3,
                                        m, mh);

    dim3 gC(NROWS / 128, DDIM / 128);  // 48 x 8
    concepts_mfma<<<gC, 256, 0, stream>>>(Abf, BbfT, rowtok, noun_b, concepts);

    dim3 g13(BDIM / 32, DDIM / 32, 2);  // 12 x 32 x 2
    emgemm13<<<g13, 128, 0, stream>>>(mh, WT1, WT3, em_b1, tr_b, hh, Tr);

    dim3 gG(BDIM / 32, DDIM / 32);      // 12 x 32
    emgemm2<<<gG, 128, 0, stream>>>(hh, WT2, em_b2, S2);

    rowops<<<BDIM, 256, 0, stream>>>(S2, Tr, r, t, uh, vh, rh, th, t2h, inv_r, inv_t);

    dim3 gS(BDIM / 32, BDIM / 32);      // 12 x 12
    score_mfma<<<gS, 128, 0, stream>>>(uh, vh, rh, th, t2h, inv_r, inv_t, score);
}